// Round 1
// baseline (729.530 us; speedup 1.0000x reference)
//
#include <hip/hip_runtime.h>

#define NP 401          // tokens incl. CLS (400 patches, side=20, add=0)
#define DIM 512
#define HEADS 8
#define HD 64
#define CPBH 512
#define LN_EPS 1e-5f
#define ATT_SCALE 0.125f  // 64^-0.5

// ---------------------------------------------------------------------------
// Generic tiled GEMM: C[z] = epilogue(scale * A[z] @ B[z])
//   epilogue: + bias[n] (opt) + resid[z][m][n] (opt), relu (opt)
//   TRANSB=false: B is K x N (ldb);  TRANSB=true: B is N x K (ldb) -> C=A@B^T
// 64x64 tile, 256 threads, 4x4 micro-tile, K-tile 16.
// ---------------------------------------------------------------------------
template<bool TRANSB>
__global__ __launch_bounds__(256) void gemm_kernel(
    const float* __restrict__ A, int lda, long aBatch,
    const float* __restrict__ B, int ldb, long bBatch,
    const float* __restrict__ bias,
    const float* __restrict__ resid, int ldr, long rBatch,
    float* __restrict__ C, int ldc, long cBatch,
    int M, int N, int K, float scale, int doRelu)
{
    __shared__ float as[16][68];   // [k][m], stride 68 floats = 272B (16B aligned rows)
    __shared__ float bs[16][68];   // [k][n]
    const int z = blockIdx.z;
    A += z * aBatch;
    B += z * bBatch;
    C += z * cBatch;
    const float* res = resid ? resid + z * rBatch : nullptr;
    const int m0 = blockIdx.x * 64, n0 = blockIdx.y * 64;
    const int tid = threadIdx.x;
    const int tx = tid & 15, ty = tid >> 4;
    float acc[4][4] = {};

    for (int k0 = 0; k0 < K; k0 += 16) {
        {   // stage A tile transposed: as[k][m]
            int row = tid >> 2, q = tid & 3;
            int gm = m0 + row;
            #pragma unroll
            for (int j = 0; j < 4; ++j) {
                int kk = q * 4 + j, gk = k0 + kk;
                as[kk][row] = (gm < M && gk < K) ? A[(long)gm * lda + gk] : 0.f;
            }
        }
        if (!TRANSB) {  // stage B tile: bs[k][n], coalesced along n
            int krow = tid >> 4, nq = tid & 15;
            int gk = k0 + krow;
            #pragma unroll
            for (int j = 0; j < 4; ++j) {
                int n = nq * 4 + j, gn = n0 + n;
                bs[krow][n] = (gk < K && gn < N) ? B[(long)gk * ldb + gn] : 0.f;
            }
        } else {        // B is N x K: read rows of B, transpose into bs[k][n]
            int row = tid >> 2, q = tid & 3;
            int gn = n0 + row;
            #pragma unroll
            for (int j = 0; j < 4; ++j) {
                int kk = q * 4 + j, gk = k0 + kk;
                bs[kk][row] = (gn < N && gk < K) ? B[(long)gn * ldb + gk] : 0.f;
            }
        }
        __syncthreads();
        #pragma unroll
        for (int kk = 0; kk < 16; ++kk) {
            float4 a4 = *(const float4*)&as[kk][ty * 4];
            float4 b4 = *(const float4*)&bs[kk][tx * 4];
            float av[4] = {a4.x, a4.y, a4.z, a4.w};
            float bv[4] = {b4.x, b4.y, b4.z, b4.w};
            #pragma unroll
            for (int r = 0; r < 4; ++r)
                #pragma unroll
                for (int c = 0; c < 4; ++c)
                    acc[r][c] = fmaf(av[r], bv[c], acc[r][c]);
        }
        __syncthreads();
    }

    #pragma unroll
    for (int r = 0; r < 4; ++r) {
        int m = m0 + ty * 4 + r;
        if (m >= M) continue;
        #pragma unroll
        for (int c = 0; c < 4; ++c) {
            int n = n0 + tx * 4 + c;
            if (n >= N) continue;
            float v = acc[r][c] * scale;
            if (bias) v += bias[n];
            if (res)  v += res[(long)m * ldr + n];
            if (doRelu) v = fmaxf(v, 0.f);
            C[(long)m * ldc + n] = v;
        }
    }
}

// ---------------------------------------------------------------------------
// CPB relative-position-bias MLP: for every pair (i,j) of the 401 tokens,
//   rel = unit(coord_i - coord_j);  bias[h][i][j] = w2^T relu(rel @ w1 + b1) + b2
// One thread per pair; weights read with uniform index (compiler -> s_load).
// ---------------------------------------------------------------------------
__global__ __launch_bounds__(256) void cpb_kernel(
    const float* __restrict__ coords,   // (400,2); token 0 is CLS at (0,0)
    const float* __restrict__ w1,       // (2,512)
    const float* __restrict__ b1,       // (512)
    const float* __restrict__ w2,       // (512,8)
    const float* __restrict__ b2,       // (8)
    float* __restrict__ biasOut)        // (8,401,401)
{
    int p = blockIdx.x * 256 + threadIdx.x;
    if (p >= NP * NP) return;
    int i = p / NP, j = p - i * NP;
    float xi = (i == 0) ? 0.f : coords[(i - 1) * 2];
    float yi = (i == 0) ? 0.f : coords[(i - 1) * 2 + 1];
    float xj = (j == 0) ? 0.f : coords[(j - 1) * 2];
    float yj = (j == 0) ? 0.f : coords[(j - 1) * 2 + 1];
    float rx = xi - xj, ry = yi - yj;
    float inv = 1.f / (sqrtf(rx * rx + ry * ry) + 1e-6f);
    float u = rx * inv, v = ry * inv;

    float acc[8] = {};
    #pragma unroll 4
    for (int k = 0; k < CPBH; ++k) {
        float hk = fmaf(u, w1[k], fmaf(v, w1[CPBH + k], b1[k]));
        hk = fmaxf(hk, 0.f);
        #pragma unroll
        for (int h = 0; h < 8; ++h)
            acc[h] = fmaf(hk, w2[k * 8 + h], acc[h]);
    }
    #pragma unroll
    for (int h = 0; h < 8; ++h)
        biasOut[(long)h * NP * NP + p] = acc[h] + b2[h];
}

// ---------------------------------------------------------------------------
// LayerNorm over DIM=512, one block (256 thr) per row.
// ---------------------------------------------------------------------------
__global__ __launch_bounds__(256) void ln_kernel(
    const float* __restrict__ x, const float* __restrict__ g,
    const float* __restrict__ b, float* __restrict__ y)
{
    int r = blockIdx.x, t = threadIdx.x;
    const float* xr = x + (long)r * DIM;
    float x0 = xr[t], x1 = xr[t + 256];
    float s = x0 + x1, sq = x0 * x0 + x1 * x1;
    #pragma unroll
    for (int off = 32; off > 0; off >>= 1) {
        s += __shfl_down(s, off);
        sq += __shfl_down(sq, off);
    }
    __shared__ float ps[4], pq[4];
    int w = t >> 6, lane = t & 63;
    if (lane == 0) { ps[w] = s; pq[w] = sq; }
    __syncthreads();
    float S = ps[0] + ps[1] + ps[2] + ps[3];
    float Q = pq[0] + pq[1] + pq[2] + pq[3];
    float mean = S * (1.f / DIM);
    float var = Q * (1.f / DIM) - mean * mean;
    float inv = rsqrtf(var + LN_EPS);
    float* yr = y + (long)r * DIM;
    yr[t]       = (x0 - mean) * inv * g[t] + b[t];
    yr[t + 256] = (x1 - mean) * inv * g[t + 256] + b[t + 256];
}

// ---------------------------------------------------------------------------
// Softmax over last axis of S (8,401,401), in place. blockIdx: (i, h)
// ---------------------------------------------------------------------------
__global__ __launch_bounds__(256) void softmax_kernel(float* __restrict__ S)
{
    long base = ((long)blockIdx.y * NP + blockIdx.x) * NP;
    int t = threadIdx.x;
    float v0 = (t < NP) ? S[base + t] : -INFINITY;
    float v1 = (t + 256 < NP) ? S[base + t + 256] : -INFINITY;
    float m = fmaxf(v0, v1);
    #pragma unroll
    for (int off = 32; off > 0; off >>= 1) m = fmaxf(m, __shfl_down(m, off));
    __shared__ float pm[4], psum[4];
    int w = t >> 6, lane = t & 63;
    if (lane == 0) pm[w] = m;
    __syncthreads();
    float M4 = fmaxf(fmaxf(pm[0], pm[1]), fmaxf(pm[2], pm[3]));
    float e0 = (t < NP) ? __expf(v0 - M4) : 0.f;
    float e1 = (t + 256 < NP) ? __expf(v1 - M4) : 0.f;
    float s = e0 + e1;
    #pragma unroll
    for (int off = 32; off > 0; off >>= 1) s += __shfl_down(s, off);
    if (lane == 0) psum[w] = s;
    __syncthreads();
    float inv = 1.f / (psum[0] + psum[1] + psum[2] + psum[3]);
    if (t < NP)       S[base + t] = e0 * inv;
    if (t + 256 < NP) S[base + t + 256] = e1 * inv;
}

// CLS token -> row 0 of h0
__global__ void cls_kernel(const float* __restrict__ cls, float* __restrict__ h0)
{
    ((float4*)h0)[threadIdx.x] = ((const float4*)cls)[threadIdx.x];
}

// Final: LN(h0 row 0) @ fc2_w + fc2_b -> out[2]
__global__ __launch_bounds__(256) void final_kernel(
    const float* __restrict__ h0, const float* __restrict__ g,
    const float* __restrict__ b, const float* __restrict__ w,
    const float* __restrict__ fb, float* __restrict__ out)
{
    int t = threadIdx.x;
    float x0 = h0[t], x1 = h0[t + 256];
    float s = x0 + x1, sq = x0 * x0 + x1 * x1;
    #pragma unroll
    for (int off = 32; off > 0; off >>= 1) {
        s += __shfl_down(s, off);
        sq += __shfl_down(sq, off);
    }
    __shared__ float ps[4], pq[4], pc0[4], pc1[4];
    int wv = t >> 6, lane = t & 63;
    if (lane == 0) { ps[wv] = s; pq[wv] = sq; }
    __syncthreads();
    float S = ps[0] + ps[1] + ps[2] + ps[3];
    float Q = pq[0] + pq[1] + pq[2] + pq[3];
    float mean = S * (1.f / DIM);
    float var = Q * (1.f / DIM) - mean * mean;
    float inv = rsqrtf(var + LN_EPS);
    float xh0 = (x0 - mean) * inv * g[t] + b[t];
    float xh1 = (x1 - mean) * inv * g[t + 256] + b[t + 256];
    float c0 = xh0 * w[t * 2]     + xh1 * w[(t + 256) * 2];
    float c1 = xh0 * w[t * 2 + 1] + xh1 * w[(t + 256) * 2 + 1];
    #pragma unroll
    for (int off = 32; off > 0; off >>= 1) {
        c0 += __shfl_down(c0, off);
        c1 += __shfl_down(c1, off);
    }
    if (lane == 0) { pc0[wv] = c0; pc1[wv] = c1; }
    __syncthreads();
    if (t == 0) {
        out[0] = pc0[0] + pc0[1] + pc0[2] + pc0[3] + fb[0];
        out[1] = pc1[0] + pc1[1] + pc1[2] + pc1[3] + fb[1];
    }
}

// ---------------------------------------------------------------------------
extern "C" void kernel_launch(void* const* d_in, const int* in_sizes, int n_in,
                              void* d_out, int out_size, void* d_ws, size_t ws_size,
                              hipStream_t stream)
{
    const float* h      = (const float*)d_in[0];   // (1,400,1024)
    const float* coords = (const float*)d_in[1];   // (1,400,2)
    const float* fc1_w  = (const float*)d_in[2];   // (1024,512)
    const float* fc1_b  = (const float*)d_in[3];
    const float* cls    = (const float*)d_in[4];   // (1,1,512)
    const float* norm_g = (const float*)d_in[25];
    const float* norm_b = (const float*)d_in[26];
    const float* fc2_w  = (const float*)d_in[27];  // (512,2)
    const float* fc2_b  = (const float*)d_in[28];

    float* ws  = (float*)d_ws;
    float* h0  = ws;                               // (401,512)
    float* xln = h0  + (long)NP * DIM;             // (401,512)
    float* qkv = xln + (long)NP * DIM;             // (401,1536)
    float* att = qkv + (long)NP * 3 * DIM;         // (401,512)
    float* S   = att + (long)NP * DIM;             // (8,401,401)
    float* bb  = S   + (long)HEADS * NP * NP;      // (8,401,401)

    // fc1 + relu into h0 rows 1..400; CLS into row 0
    gemm_kernel<false><<<dim3(7, 8, 1), 256, 0, stream>>>(
        h, 1024, 0, fc1_w, 512, 0, fc1_b, nullptr, 0, 0,
        h0 + DIM, DIM, 0, 400, DIM, 1024, 1.f, 1);
    cls_kernel<<<1, 128, 0, stream>>>(cls, h0);

    for (int l = 0; l < 2; ++l) {
        int base = 5 + 10 * l;
        const float* ng     = (const float*)d_in[base + 0];
        const float* nb     = (const float*)d_in[base + 1];
        const float* cpb_w1 = (const float*)d_in[base + 2];
        const float* cpb_b1 = (const float*)d_in[base + 3];
        const float* cpb_w2 = (const float*)d_in[base + 4];
        const float* cpb_b2 = (const float*)d_in[base + 5];
        const float* qkv_w  = (const float*)d_in[base + 6];
        const float* qkv_b  = (const float*)d_in[base + 7];
        const float* proj_w = (const float*)d_in[base + 8];
        const float* proj_b = (const float*)d_in[base + 9];

        ln_kernel<<<NP, 256, 0, stream>>>(h0, ng, nb, xln);

        gemm_kernel<false><<<dim3(7, 24, 1), 256, 0, stream>>>(
            xln, DIM, 0, qkv_w, 3 * DIM, 0, qkv_b, nullptr, 0, 0,
            qkv, 3 * DIM, 0, NP, 3 * DIM, DIM, 1.f, 0);

        cpb_kernel<<<(NP * NP + 255) / 256, 256, 0, stream>>>(
            coords, cpb_w1, cpb_b1, cpb_w2, cpb_b2, bb);

        // S[h] = ATT_SCALE * q_h @ k_h^T + bias_h    (q,k strided slices of qkv)
        gemm_kernel<true><<<dim3(7, 7, HEADS), 256, 0, stream>>>(
            qkv, 3 * DIM, HD,                 // A = q slice, head batch = 64 cols
            qkv + DIM, 3 * DIM, HD,           // B = k slice (N x K, transposed)
            nullptr, bb, NP, (long)NP * NP,   // resid = cpb bias
            S, NP, (long)NP * NP,
            NP, NP, HD, ATT_SCALE, 0);

        softmax_kernel<<<dim3(NP, HEADS), 256, 0, stream>>>(S);

        // att[:, h*64:(h+1)*64] = P_h @ v_h
        gemm_kernel<false><<<dim3(7, 1, HEADS), 256, 0, stream>>>(
            S, NP, (long)NP * NP,
            qkv + 2 * DIM, 3 * DIM, HD,
            nullptr, nullptr, 0, 0,
            att, DIM, HD,
            NP, HD, NP, 1.f, 0);

        // h0 = h0 + att @ proj_w + proj_b
        gemm_kernel<false><<<dim3(7, 8, 1), 256, 0, stream>>>(
            att, DIM, 0, proj_w, DIM, 0, proj_b, h0, DIM, 0,
            h0, DIM, 0, NP, DIM, DIM, 1.f, 0);
    }

    final_kernel<<<1, 256, 0, stream>>>(h0, norm_g, norm_b, fc2_w, fc2_b,
                                        (float*)d_out);
}

// Round 2
// 405.472 us; speedup vs baseline: 1.7992x; 1.7992x over previous
//
#include <hip/hip_runtime.h>

#define NP 401          // tokens incl. CLS (400 patches, side=20, add=0)
#define DIM 512
#define HEADS 8
#define HD 64
#define CPBH 512
#define LN_EPS 1e-5f
#define ATT_SCALE 0.125f  // 64^-0.5
#define SP 416            // padded row stride for S / bias planes (16B-aligned)
#define PLANE (NP * SP)   // 401*416 floats per head plane

// ---------------------------------------------------------------------------
// Tiled GEMM, latency-tolerant: C[z] = epilogue(scale * A[z] @ B[z])
//   TM=32, TN=64, KT=16, 256 threads, 2x4 micro-tile.
//   Register double-buffer: global loads for tile k+1 issued before compute
//   of tile k (latency hides behind FMAs + barrier).
//   TRANSB=false: B is K x N;  TRANSB=true: B is N x K -> C = A @ B^T
// ---------------------------------------------------------------------------
template<bool TRANSB>
__global__ __launch_bounds__(256) void gemm_kernel(
    const float* __restrict__ A, int lda, long aBatch,
    const float* __restrict__ B, int ldb, long bBatch,
    const float* __restrict__ bias,
    const float* __restrict__ resid, int ldr, long rBatch,
    float* __restrict__ C, int ldc, long cBatch,
    int M, int N, int K, float scale, int doRelu)
{
    __shared__ float as[16][34];   // [k][m], even stride -> aligned b64 reads
    __shared__ float bs[16][68];   // [k][n]
    const int z = blockIdx.z;
    A += z * aBatch;
    B += z * bBatch;
    C += z * cBatch;
    const float* res = resid ? resid + z * rBatch : nullptr;
    const int m0 = blockIdx.x * 32, n0 = blockIdx.y * 64;
    const int tid = threadIdx.x;
    const int tx = tid & 15;      // n-quad: cols tx*4 .. tx*4+3
    const int ty = tid >> 4;      // rows ty*2, ty*2+1

    // A staging (threads 0..127): float4 along k
    const int arow = tid >> 2, aq = tid & 3;
    // B staging (!TRANSB): float4 along n
    const int bk = tid >> 4, bnq = tid & 15;
    // B staging (TRANSB): float4 along k, row = n
    const int brow = tid >> 2, bq = tid & 3;

    float acc[2][4] = {{0.f,0.f,0.f,0.f},{0.f,0.f,0.f,0.f}};
    float aR[4] = {0.f,0.f,0.f,0.f};
    float bR[4] = {0.f,0.f,0.f,0.f};

    auto loadA = [&](int k0, float r[4]) {
        r[0] = r[1] = r[2] = r[3] = 0.f;
        if (tid < 128) {
            int gm = m0 + arow;
            if (gm < M) {
                int gk = k0 + aq * 4;
                const float* p = A + (long)gm * lda + gk;
                if (gk + 3 < K) {
                    float4 v = *(const float4*)p;
                    r[0] = v.x; r[1] = v.y; r[2] = v.z; r[3] = v.w;
                } else {
                    if (gk     < K) r[0] = p[0];
                    if (gk + 1 < K) r[1] = p[1];
                    if (gk + 2 < K) r[2] = p[2];
                    if (gk + 3 < K) r[3] = p[3];
                }
            }
        }
    };
    auto loadB = [&](int k0, float r[4]) {
        r[0] = r[1] = r[2] = r[3] = 0.f;
        if (!TRANSB) {
            int gk = k0 + bk;
            if (gk < K) {
                int gn = n0 + bnq * 4;
                const float* p = B + (long)gk * ldb + gn;
                if (gn + 3 < N) {
                    float4 v = *(const float4*)p;
                    r[0] = v.x; r[1] = v.y; r[2] = v.z; r[3] = v.w;
                } else {
                    if (gn     < N) r[0] = p[0];
                    if (gn + 1 < N) r[1] = p[1];
                    if (gn + 2 < N) r[2] = p[2];
                    if (gn + 3 < N) r[3] = p[3];
                }
            }
        } else {
            int gn = n0 + brow;
            if (gn < N) {
                int gk = k0 + bq * 4;
                const float* p = B + (long)gn * ldb + gk;
                if (gk + 3 < K) {
                    float4 v = *(const float4*)p;
                    r[0] = v.x; r[1] = v.y; r[2] = v.z; r[3] = v.w;
                } else {
                    if (gk     < K) r[0] = p[0];
                    if (gk + 1 < K) r[1] = p[1];
                    if (gk + 2 < K) r[2] = p[2];
                    if (gk + 3 < K) r[3] = p[3];
                }
            }
        }
    };

    loadA(0, aR);
    loadB(0, bR);

    for (int k0 = 0; k0 < K; k0 += 16) {
        // commit staged registers to LDS
        if (tid < 128) {
            as[aq * 4 + 0][arow] = aR[0];
            as[aq * 4 + 1][arow] = aR[1];
            as[aq * 4 + 2][arow] = aR[2];
            as[aq * 4 + 3][arow] = aR[3];
        }
        if (!TRANSB) {
            *(float4*)&bs[bk][bnq * 4] = make_float4(bR[0], bR[1], bR[2], bR[3]);
        } else {
            bs[bq * 4 + 0][brow] = bR[0];
            bs[bq * 4 + 1][brow] = bR[1];
            bs[bq * 4 + 2][brow] = bR[2];
            bs[bq * 4 + 3][brow] = bR[3];
        }
        __syncthreads();

        // prefetch next tile while computing this one
        float nA[4] = {0.f,0.f,0.f,0.f};
        float nB[4] = {0.f,0.f,0.f,0.f};
        if (k0 + 16 < K) {
            loadA(k0 + 16, nA);
            loadB(k0 + 16, nB);
        }

        #pragma unroll
        for (int kk = 0; kk < 16; ++kk) {
            float2 a2 = *(const float2*)&as[kk][ty * 2];   // broadcast, 4 addrs/wave
            float4 b4 = *(const float4*)&bs[kk][tx * 4];
            acc[0][0] = fmaf(a2.x, b4.x, acc[0][0]);
            acc[0][1] = fmaf(a2.x, b4.y, acc[0][1]);
            acc[0][2] = fmaf(a2.x, b4.z, acc[0][2]);
            acc[0][3] = fmaf(a2.x, b4.w, acc[0][3]);
            acc[1][0] = fmaf(a2.y, b4.x, acc[1][0]);
            acc[1][1] = fmaf(a2.y, b4.y, acc[1][1]);
            acc[1][2] = fmaf(a2.y, b4.z, acc[1][2]);
            acc[1][3] = fmaf(a2.y, b4.w, acc[1][3]);
        }
        __syncthreads();

        aR[0] = nA[0]; aR[1] = nA[1]; aR[2] = nA[2]; aR[3] = nA[3];
        bR[0] = nB[0]; bR[1] = nB[1]; bR[2] = nB[2]; bR[3] = nB[3];
    }

    #pragma unroll
    for (int r = 0; r < 2; ++r) {
        int m = m0 + ty * 2 + r;
        if (m >= M) continue;
        #pragma unroll
        for (int c = 0; c < 4; ++c) {
            int n = n0 + tx * 4 + c;
            if (n >= N) continue;
            float v = acc[r][c] * scale;
            if (bias) v += bias[n];
            if (res)  v += res[(long)m * ldr + n];
            if (doRelu) v = fmaxf(v, 0.f);
            C[(long)m * ldc + n] = v;
        }
    }
}

// ---------------------------------------------------------------------------
// CPB relative-position-bias MLP: bias[h][i][j] for every token pair.
// One thread per pair; weights read with uniform index (s_load broadcast).
// Output planes padded to row stride SP.
// ---------------------------------------------------------------------------
__global__ __launch_bounds__(256) void cpb_kernel(
    const float* __restrict__ coords,   // (400,2); token 0 is CLS at (0,0)
    const float* __restrict__ w1,       // (2,512)
    const float* __restrict__ b1,       // (512)
    const float* __restrict__ w2,       // (512,8)
    const float* __restrict__ b2,       // (8)
    float* __restrict__ biasOut)        // (8, NP, SP)
{
    int p = blockIdx.x * 256 + threadIdx.x;
    if (p >= NP * NP) return;
    int i = p / NP, j = p - i * NP;
    float xi = (i == 0) ? 0.f : coords[(i - 1) * 2];
    float yi = (i == 0) ? 0.f : coords[(i - 1) * 2 + 1];
    float xj = (j == 0) ? 0.f : coords[(j - 1) * 2];
    float yj = (j == 0) ? 0.f : coords[(j - 1) * 2 + 1];
    float rx = xi - xj, ry = yi - yj;
    float inv = 1.f / (sqrtf(rx * rx + ry * ry) + 1e-6f);
    float u = rx * inv, v = ry * inv;

    float acc[8] = {};
    #pragma unroll 4
    for (int k = 0; k < CPBH; ++k) {
        float hk = fmaf(u, w1[k], fmaf(v, w1[CPBH + k], b1[k]));
        hk = fmaxf(hk, 0.f);
        #pragma unroll
        for (int h = 0; h < 8; ++h)
            acc[h] = fmaf(hk, w2[k * 8 + h], acc[h]);
    }
    long rowBase = (long)i * SP + j;
    #pragma unroll
    for (int h = 0; h < 8; ++h)
        biasOut[(long)h * PLANE + rowBase] = acc[h] + b2[h];
}

// ---------------------------------------------------------------------------
// LayerNorm over DIM=512, one block (256 thr) per row.
// ---------------------------------------------------------------------------
__global__ __launch_bounds__(256) void ln_kernel(
    const float* __restrict__ x, const float* __restrict__ g,
    const float* __restrict__ b, float* __restrict__ y)
{
    int r = blockIdx.x, t = threadIdx.x;
    const float* xr = x + (long)r * DIM;
    float x0 = xr[t], x1 = xr[t + 256];
    float s = x0 + x1, sq = x0 * x0 + x1 * x1;
    #pragma unroll
    for (int off = 32; off > 0; off >>= 1) {
        s += __shfl_down(s, off);
        sq += __shfl_down(sq, off);
    }
    __shared__ float ps[4], pq[4];
    int w = t >> 6, lane = t & 63;
    if (lane == 0) { ps[w] = s; pq[w] = sq; }
    __syncthreads();
    float S = ps[0] + ps[1] + ps[2] + ps[3];
    float Q = pq[0] + pq[1] + pq[2] + pq[3];
    float mean = S * (1.f / DIM);
    float var = Q * (1.f / DIM) - mean * mean;
    float inv = rsqrtf(var + LN_EPS);
    float* yr = y + (long)r * DIM;
    yr[t]       = (x0 - mean) * inv * g[t] + b[t];
    yr[t + 256] = (x1 - mean) * inv * g[t + 256] + b[t + 256];
}

// ---------------------------------------------------------------------------
// Softmax over last axis of S (8, NP, SP) rows of 401, in place.
// blockIdx: (i, h)
// ---------------------------------------------------------------------------
__global__ __launch_bounds__(256) void softmax_kernel(float* __restrict__ S)
{
    long base = (long)blockIdx.y * PLANE + (long)blockIdx.x * SP;
    int t = threadIdx.x;
    float v0 = (t < NP) ? S[base + t] : -INFINITY;
    float v1 = (t + 256 < NP) ? S[base + t + 256] : -INFINITY;
    float m = fmaxf(v0, v1);
    #pragma unroll
    for (int off = 32; off > 0; off >>= 1) m = fmaxf(m, __shfl_down(m, off));
    __shared__ float pm[4], psum[4];
    int w = t >> 6, lane = t & 63;
    if (lane == 0) pm[w] = m;
    __syncthreads();
    float M4 = fmaxf(fmaxf(pm[0], pm[1]), fmaxf(pm[2], pm[3]));
    float e0 = (t < NP) ? __expf(v0 - M4) : 0.f;
    float e1 = (t + 256 < NP) ? __expf(v1 - M4) : 0.f;
    float s = e0 + e1;
    #pragma unroll
    for (int off = 32; off > 0; off >>= 1) s += __shfl_down(s, off);
    if (lane == 0) psum[w] = s;
    __syncthreads();
    float inv = 1.f / (psum[0] + psum[1] + psum[2] + psum[3]);
    if (t < NP)       S[base + t] = e0 * inv;
    if (t + 256 < NP) S[base + t + 256] = e1 * inv;
}

// CLS token -> row 0 of h0
__global__ void cls_kernel(const float* __restrict__ cls, float* __restrict__ h0)
{
    ((float4*)h0)[threadIdx.x] = ((const float4*)cls)[threadIdx.x];
}

// Final: LN(h0 row 0) @ fc2_w + fc2_b -> out[2]
__global__ __launch_bounds__(256) void final_kernel(
    const float* __restrict__ h0, const float* __restrict__ g,
    const float* __restrict__ b, const float* __restrict__ w,
    const float* __restrict__ fb, float* __restrict__ out)
{
    int t = threadIdx.x;
    float x0 = h0[t], x1 = h0[t + 256];
    float s = x0 + x1, sq = x0 * x0 + x1 * x1;
    #pragma unroll
    for (int off = 32; off > 0; off >>= 1) {
        s += __shfl_down(s, off);
        sq += __shfl_down(sq, off);
    }
    __shared__ float ps[4], pq[4], pc0[4], pc1[4];
    int wv = t >> 6, lane = t & 63;
    if (lane == 0) { ps[wv] = s; pq[wv] = sq; }
    __syncthreads();
    float S = ps[0] + ps[1] + ps[2] + ps[3];
    float Q = pq[0] + pq[1] + pq[2] + pq[3];
    float mean = S * (1.f / DIM);
    float var = Q * (1.f / DIM) - mean * mean;
    float inv = rsqrtf(var + LN_EPS);
    float xh0 = (x0 - mean) * inv * g[t] + b[t];
    float xh1 = (x1 - mean) * inv * g[t + 256] + b[t + 256];
    float c0 = xh0 * w[t * 2]     + xh1 * w[(t + 256) * 2];
    float c1 = xh0 * w[t * 2 + 1] + xh1 * w[(t + 256) * 2 + 1];
    #pragma unroll
    for (int off = 32; off > 0; off >>= 1) {
        c0 += __shfl_down(c0, off);
        c1 += __shfl_down(c1, off);
    }
    if (lane == 0) { pc0[wv] = c0; pc1[wv] = c1; }
    __syncthreads();
    if (t == 0) {
        out[0] = pc0[0] + pc0[1] + pc0[2] + pc0[3] + fb[0];
        out[1] = pc1[0] + pc1[1] + pc1[2] + pc1[3] + fb[1];
    }
}

// ---------------------------------------------------------------------------
extern "C" void kernel_launch(void* const* d_in, const int* in_sizes, int n_in,
                              void* d_out, int out_size, void* d_ws, size_t ws_size,
                              hipStream_t stream)
{
    const float* h      = (const float*)d_in[0];   // (1,400,1024)
    const float* coords = (const float*)d_in[1];   // (1,400,2)
    const float* fc1_w  = (const float*)d_in[2];   // (1024,512)
    const float* fc1_b  = (const float*)d_in[3];
    const float* cls    = (const float*)d_in[4];   // (1,1,512)
    const float* norm_g = (const float*)d_in[25];
    const float* norm_b = (const float*)d_in[26];
    const float* fc2_w  = (const float*)d_in[27];  // (512,2)
    const float* fc2_b  = (const float*)d_in[28];

    float* ws  = (float*)d_ws;
    float* h0  = ws;                               // (401,512)
    float* xln = h0  + (long)NP * DIM;             // (401,512)
    float* qkv = xln + (long)NP * DIM;             // (401,1536)
    float* att = qkv + (long)NP * 3 * DIM;         // (401,512)
    float* S   = att + (long)NP * DIM;             // (8,NP,SP)
    float* bb  = S   + (long)HEADS * PLANE;        // (8,NP,SP)

    // fc1 + relu into h0 rows 1..400; CLS into row 0
    gemm_kernel<false><<<dim3(13, 8, 1), 256, 0, stream>>>(
        h, 1024, 0, fc1_w, 512, 0, fc1_b, nullptr, 0, 0,
        h0 + DIM, DIM, 0, 400, DIM, 1024, 1.f, 1);
    cls_kernel<<<1, 128, 0, stream>>>(cls, h0);

    for (int l = 0; l < 2; ++l) {
        int base = 5 + 10 * l;
        const float* ng     = (const float*)d_in[base + 0];
        const float* nb     = (const float*)d_in[base + 1];
        const float* cpb_w1 = (const float*)d_in[base + 2];
        const float* cpb_b1 = (const float*)d_in[base + 3];
        const float* cpb_w2 = (const float*)d_in[base + 4];
        const float* cpb_b2 = (const float*)d_in[base + 5];
        const float* qkv_w  = (const float*)d_in[base + 6];
        const float* qkv_b  = (const float*)d_in[base + 7];
        const float* proj_w = (const float*)d_in[base + 8];
        const float* proj_b = (const float*)d_in[base + 9];

        ln_kernel<<<NP, 256, 0, stream>>>(h0, ng, nb, xln);

        gemm_kernel<false><<<dim3(13, 24, 1), 256, 0, stream>>>(
            xln, DIM, 0, qkv_w, 3 * DIM, 0, qkv_b, nullptr, 0, 0,
            qkv, 3 * DIM, 0, NP, 3 * DIM, DIM, 1.f, 0);

        cpb_kernel<<<(NP * NP + 255) / 256, 256, 0, stream>>>(
            coords, cpb_w1, cpb_b1, cpb_w2, cpb_b2, bb);

        // S[h] = ATT_SCALE * q_h @ k_h^T + bias_h
        gemm_kernel<true><<<dim3(13, 7, HEADS), 256, 0, stream>>>(
            qkv, 3 * DIM, HD,                 // A = q slice
            qkv + DIM, 3 * DIM, HD,           // B = k slice (N x K)
            nullptr, bb, SP, (long)PLANE,     // resid = cpb bias
            S, SP, (long)PLANE,
            NP, NP, HD, ATT_SCALE, 0);

        softmax_kernel<<<dim3(NP, HEADS), 256, 0, stream>>>(S);

        // att[:, h*64:(h+1)*64] = P_h @ v_h
        gemm_kernel<false><<<dim3(13, 1, HEADS), 256, 0, stream>>>(
            S, SP, (long)PLANE,
            qkv + 2 * DIM, 3 * DIM, HD,
            nullptr, nullptr, 0, 0,
            att, DIM, HD,
            NP, HD, NP, 1.f, 0);

        // h0 = h0 + att @ proj_w + proj_b
        gemm_kernel<false><<<dim3(13, 8, 1), 256, 0, stream>>>(
            att, DIM, 0, proj_w, DIM, 0, proj_b, h0, DIM, 0,
            h0, DIM, 0, NP, DIM, DIM, 1.f, 0);
    }

    final_kernel<<<1, 256, 0, stream>>>(h0, norm_g, norm_b, fc2_w, fc2_b,
                                        (float*)d_out);
}

// Round 3
// 361.010 us; speedup vs baseline: 2.0208x; 1.1232x over previous
//
#include <hip/hip_runtime.h>
#include <math.h>

#define NP 401          // tokens incl. CLS (400 patches, side=20, add=0)
#define DIM 512
#define HEADS 8
#define HD 64
#define CPBH 512
#define LN_EPS 1e-5f
#define ATT_SCALE 0.125f  // 64^-0.5
#define SP 416            // padded row stride for S planes (16B-aligned)
#define PLANE (NP * SP)   // floats per head plane
#define CPB_M 16384       // angle-table resolution
#define CPB_TROWS (CPB_M + 64)   // + zero-vector entry block

// ---------------------------------------------------------------------------
// Tiled GEMM, latency-tolerant: C[z] = epilogue(scale * A[z] @ B[z])
//   TM=32, TN=64, KT=16, 256 threads, 2x4 micro-tile, register double-buffer.
//   TRANSB=false: B is K x N;  TRANSB=true: B is N x K -> C = A @ B^T
// ---------------------------------------------------------------------------
template<bool TRANSB>
__global__ __launch_bounds__(256) void gemm_kernel(
    const float* __restrict__ A, int lda, long aBatch,
    const float* __restrict__ B, int ldb, long bBatch,
    const float* __restrict__ bias,
    const float* __restrict__ resid, int ldr, long rBatch,
    float* __restrict__ C, int ldc, long cBatch,
    int M, int N, int K, float scale, int doRelu)
{
    __shared__ float as[16][34];   // [k][m]
    __shared__ float bs[16][68];   // [k][n]
    const int z = blockIdx.z;
    A += z * aBatch;
    B += z * bBatch;
    C += z * cBatch;
    const float* res = resid ? resid + z * rBatch : nullptr;
    const int m0 = blockIdx.x * 32, n0 = blockIdx.y * 64;
    const int tid = threadIdx.x;
    const int tx = tid & 15;      // n-quad
    const int ty = tid >> 4;      // m-pair

    const int arow = tid >> 2, aq = tid & 3;
    const int bk = tid >> 4, bnq = tid & 15;
    const int brow = tid >> 2, bq = tid & 3;

    float acc[2][4] = {{0.f,0.f,0.f,0.f},{0.f,0.f,0.f,0.f}};
    float aR[4] = {0.f,0.f,0.f,0.f};
    float bR[4] = {0.f,0.f,0.f,0.f};

    auto loadA = [&](int k0, float r[4]) {
        r[0] = r[1] = r[2] = r[3] = 0.f;
        if (tid < 128) {
            int gm = m0 + arow;
            if (gm < M) {
                int gk = k0 + aq * 4;
                const float* p = A + (long)gm * lda + gk;
                if (gk + 3 < K) {
                    float4 v = *(const float4*)p;
                    r[0] = v.x; r[1] = v.y; r[2] = v.z; r[3] = v.w;
                } else {
                    if (gk     < K) r[0] = p[0];
                    if (gk + 1 < K) r[1] = p[1];
                    if (gk + 2 < K) r[2] = p[2];
                    if (gk + 3 < K) r[3] = p[3];
                }
            }
        }
    };
    auto loadB = [&](int k0, float r[4]) {
        r[0] = r[1] = r[2] = r[3] = 0.f;
        if (!TRANSB) {
            int gk = k0 + bk;
            if (gk < K) {
                int gn = n0 + bnq * 4;
                const float* p = B + (long)gk * ldb + gn;
                if (gn + 3 < N) {
                    float4 v = *(const float4*)p;
                    r[0] = v.x; r[1] = v.y; r[2] = v.z; r[3] = v.w;
                } else {
                    if (gn     < N) r[0] = p[0];
                    if (gn + 1 < N) r[1] = p[1];
                    if (gn + 2 < N) r[2] = p[2];
                    if (gn + 3 < N) r[3] = p[3];
                }
            }
        } else {
            int gn = n0 + brow;
            if (gn < N) {
                int gk = k0 + bq * 4;
                const float* p = B + (long)gn * ldb + gk;
                if (gk + 3 < K) {
                    float4 v = *(const float4*)p;
                    r[0] = v.x; r[1] = v.y; r[2] = v.z; r[3] = v.w;
                } else {
                    if (gk     < K) r[0] = p[0];
                    if (gk + 1 < K) r[1] = p[1];
                    if (gk + 2 < K) r[2] = p[2];
                    if (gk + 3 < K) r[3] = p[3];
                }
            }
        }
    };

    loadA(0, aR);
    loadB(0, bR);

    for (int k0 = 0; k0 < K; k0 += 16) {
        if (tid < 128) {
            as[aq * 4 + 0][arow] = aR[0];
            as[aq * 4 + 1][arow] = aR[1];
            as[aq * 4 + 2][arow] = aR[2];
            as[aq * 4 + 3][arow] = aR[3];
        }
        if (!TRANSB) {
            *(float4*)&bs[bk][bnq * 4] = make_float4(bR[0], bR[1], bR[2], bR[3]);
        } else {
            bs[bq * 4 + 0][brow] = bR[0];
            bs[bq * 4 + 1][brow] = bR[1];
            bs[bq * 4 + 2][brow] = bR[2];
            bs[bq * 4 + 3][brow] = bR[3];
        }
        __syncthreads();

        float nA[4] = {0.f,0.f,0.f,0.f};
        float nB[4] = {0.f,0.f,0.f,0.f};
        if (k0 + 16 < K) {
            loadA(k0 + 16, nA);
            loadB(k0 + 16, nB);
        }

        #pragma unroll
        for (int kk = 0; kk < 16; ++kk) {
            float2 a2 = *(const float2*)&as[kk][ty * 2];
            float4 b4 = *(const float4*)&bs[kk][tx * 4];
            acc[0][0] = fmaf(a2.x, b4.x, acc[0][0]);
            acc[0][1] = fmaf(a2.x, b4.y, acc[0][1]);
            acc[0][2] = fmaf(a2.x, b4.z, acc[0][2]);
            acc[0][3] = fmaf(a2.x, b4.w, acc[0][3]);
            acc[1][0] = fmaf(a2.y, b4.x, acc[1][0]);
            acc[1][1] = fmaf(a2.y, b4.y, acc[1][1]);
            acc[1][2] = fmaf(a2.y, b4.z, acc[1][2]);
            acc[1][3] = fmaf(a2.y, b4.w, acc[1][3]);
        }
        __syncthreads();

        aR[0] = nA[0]; aR[1] = nA[1]; aR[2] = nA[2]; aR[3] = nA[3];
        bR[0] = nB[0]; bR[1] = nB[1]; bR[2] = nB[2]; bR[3] = nB[3];
    }

    #pragma unroll
    for (int r = 0; r < 2; ++r) {
        int m = m0 + ty * 2 + r;
        if (m >= M) continue;
        #pragma unroll
        for (int c = 0; c < 4; ++c) {
            int n = n0 + tx * 4 + c;
            if (n >= N) continue;
            float v = acc[r][c] * scale;
            if (bias) v += bias[n];
            if (res)  v += res[(long)m * ldr + n];
            if (doRelu) v = fmaxf(v, 0.f);
            C[(long)m * ldc + n] = v;
        }
    }
}

// ---------------------------------------------------------------------------
// CPB angle table: bias depends only on direction of (coord_i - coord_j).
// T[z][a][h] = f_z(theta_a), theta_a = -pi + a * 2pi/CPB_M, a in [0, CPB_M).
// Row CPB_M holds the zero-vector case (u=v=0, i==j / coincident coords).
// Block = 256 thr = 4 waves: 64 angles (one/lane), wave w covers k in
// [w*128,(w+1)*128) -> LDS reduce. Weights are wave-uniform (scalar loads).
// blockIdx.y = layer.
// ---------------------------------------------------------------------------
__global__ __launch_bounds__(256) void cpb_table_kernel(
    const float* __restrict__ w1_0, const float* __restrict__ b1_0,
    const float* __restrict__ w2_0, const float* __restrict__ b2_0,
    const float* __restrict__ w1_1, const float* __restrict__ b1_1,
    const float* __restrict__ w2_1, const float* __restrict__ b2_1,
    float* __restrict__ T)            // (2, CPB_TROWS, 8)
{
    const int z = blockIdx.y;
    const float* __restrict__ w1 = z ? w1_1 : w1_0;
    const float* __restrict__ b1 = z ? b1_1 : b1_0;
    const float* __restrict__ w2 = z ? w2_1 : w2_0;
    const float* __restrict__ b2 = z ? b2_1 : b2_0;

    const int lane = threadIdx.x & 63;
    const int wv = threadIdx.x >> 6;
    const int a = blockIdx.x * 64 + lane;

    float ca = 0.f, sa = 0.f;
    if (blockIdx.x != CPB_M / 64) {
        float th = fmaf((float)a, (float)(2.0 * M_PI / CPB_M), -(float)M_PI);
        sincosf(th, &sa, &ca);
    }

    float acc[8] = {};
    const int kbeg = wv * 128;
    #pragma unroll 4
    for (int k = kbeg; k < kbeg + 128; ++k) {
        float hk = fmaxf(fmaf(ca, w1[k], fmaf(sa, w1[CPBH + k], b1[k])), 0.f);
        #pragma unroll
        for (int h = 0; h < 8; ++h)
            acc[h] = fmaf(hk, w2[k * 8 + h], acc[h]);
    }

    __shared__ float red[4][64][8];
    #pragma unroll
    for (int h = 0; h < 8; ++h) red[wv][lane][h] = acc[h];
    __syncthreads();
    if (threadIdx.x < 64) {
        int t = threadIdx.x;
        float* out = T + ((long)z * CPB_TROWS + blockIdx.x * 64 + t) * 8;
        #pragma unroll
        for (int h = 0; h < 8; ++h)
            out[h] = red[0][t][h] + red[1][t][h] + red[2][t][h] + red[3][t][h]
                     + b2[h];
    }
}

// ---------------------------------------------------------------------------
// Expand per-pair bias from the angle table (linear interp) directly into the
// 8 score planes of S (the QK^T GEMM then adds scores via its resid path).
// ---------------------------------------------------------------------------
__global__ __launch_bounds__(256) void cpb_pairs_kernel(
    const float* __restrict__ coords,   // (400,2); token 0 = CLS at (0,0)
    const float* __restrict__ T,        // this layer's (CPB_TROWS, 8) table
    float* __restrict__ S)              // (8, NP, SP)
{
    int p = blockIdx.x * 256 + threadIdx.x;
    if (p >= NP * NP) return;
    int i = p / NP, j = p - i * NP;
    float xi = (i == 0) ? 0.f : coords[(i - 1) * 2];
    float yi = (i == 0) ? 0.f : coords[(i - 1) * 2 + 1];
    float xj = (j == 0) ? 0.f : coords[(j - 1) * 2];
    float yj = (j == 0) ? 0.f : coords[(j - 1) * 2 + 1];
    float rx = xi - xj, ry = yi - yj;

    int m, m2;
    float frac;
    if (rx == 0.f && ry == 0.f) {
        m = CPB_M; m2 = CPB_M; frac = 0.f;     // zero-vector entry
    } else {
        float x = (atan2f(ry, rx) + 3.14159265358979f)
                  * (float)(CPB_M / (2.0 * M_PI));
        int mi = (int)x;
        frac = x - (float)mi;
        m = (mi >= CPB_M) ? mi - CPB_M : mi;
        m2 = (m + 1 >= CPB_M) ? 0 : m + 1;
    }
    float4 a0 = *(const float4*)(T + (long)m * 8);
    float4 a1 = *(const float4*)(T + (long)m * 8 + 4);
    float4 c0 = *(const float4*)(T + (long)m2 * 8);
    float4 c1 = *(const float4*)(T + (long)m2 * 8 + 4);

    long base = (long)i * SP + j;
    S[0L * PLANE + base] = fmaf(frac, c0.x - a0.x, a0.x);
    S[1L * PLANE + base] = fmaf(frac, c0.y - a0.y, a0.y);
    S[2L * PLANE + base] = fmaf(frac, c0.z - a0.z, a0.z);
    S[3L * PLANE + base] = fmaf(frac, c0.w - a0.w, a0.w);
    S[4L * PLANE + base] = fmaf(frac, c1.x - a1.x, a1.x);
    S[5L * PLANE + base] = fmaf(frac, c1.y - a1.y, a1.y);
    S[6L * PLANE + base] = fmaf(frac, c1.z - a1.z, a1.z);
    S[7L * PLANE + base] = fmaf(frac, c1.w - a1.w, a1.w);
}

// ---------------------------------------------------------------------------
// LayerNorm over DIM=512, one block (256 thr) per row.
// ---------------------------------------------------------------------------
__global__ __launch_bounds__(256) void ln_kernel(
    const float* __restrict__ x, const float* __restrict__ g,
    const float* __restrict__ b, float* __restrict__ y)
{
    int r = blockIdx.x, t = threadIdx.x;
    const float* xr = x + (long)r * DIM;
    float x0 = xr[t], x1 = xr[t + 256];
    float s = x0 + x1, sq = x0 * x0 + x1 * x1;
    #pragma unroll
    for (int off = 32; off > 0; off >>= 1) {
        s += __shfl_down(s, off);
        sq += __shfl_down(sq, off);
    }
    __shared__ float ps[4], pq[4];
    int w = t >> 6, lane = t & 63;
    if (lane == 0) { ps[w] = s; pq[w] = sq; }
    __syncthreads();
    float S = ps[0] + ps[1] + ps[2] + ps[3];
    float Q = pq[0] + pq[1] + pq[2] + pq[3];
    float mean = S * (1.f / DIM);
    float var = Q * (1.f / DIM) - mean * mean;
    float inv = rsqrtf(var + LN_EPS);
    float* yr = y + (long)r * DIM;
    yr[t]       = (x0 - mean) * inv * g[t] + b[t];
    yr[t + 256] = (x1 - mean) * inv * g[t + 256] + b[t + 256];
}

// ---------------------------------------------------------------------------
// Softmax over last axis of S (8, NP, SP) rows of 401, in place.
// ---------------------------------------------------------------------------
__global__ __launch_bounds__(256) void softmax_kernel(float* __restrict__ S)
{
    long base = (long)blockIdx.y * PLANE + (long)blockIdx.x * SP;
    int t = threadIdx.x;
    float v0 = (t < NP) ? S[base + t] : -INFINITY;
    float v1 = (t + 256 < NP) ? S[base + t + 256] : -INFINITY;
    float m = fmaxf(v0, v1);
    #pragma unroll
    for (int off = 32; off > 0; off >>= 1) m = fmaxf(m, __shfl_down(m, off));
    __shared__ float pm[4], psum[4];
    int w = t >> 6, lane = t & 63;
    if (lane == 0) pm[w] = m;
    __syncthreads();
    float M4 = fmaxf(fmaxf(pm[0], pm[1]), fmaxf(pm[2], pm[3]));
    float e0 = (t < NP) ? __expf(v0 - M4) : 0.f;
    float e1 = (t + 256 < NP) ? __expf(v1 - M4) : 0.f;
    float s = e0 + e1;
    #pragma unroll
    for (int off = 32; off > 0; off >>= 1) s += __shfl_down(s, off);
    if (lane == 0) psum[w] = s;
    __syncthreads();
    float inv = 1.f / (psum[0] + psum[1] + psum[2] + psum[3]);
    if (t < NP)       S[base + t] = e0 * inv;
    if (t + 256 < NP) S[base + t + 256] = e1 * inv;
}

// CLS token -> row 0 of h0
__global__ void cls_kernel(const float* __restrict__ cls, float* __restrict__ h0)
{
    ((float4*)h0)[threadIdx.x] = ((const float4*)cls)[threadIdx.x];
}

// Final: LN(h0 row 0) @ fc2_w + fc2_b -> out[2]
__global__ __launch_bounds__(256) void final_kernel(
    const float* __restrict__ h0, const float* __restrict__ g,
    const float* __restrict__ b, const float* __restrict__ w,
    const float* __restrict__ fb, float* __restrict__ out)
{
    int t = threadIdx.x;
    float x0 = h0[t], x1 = h0[t + 256];
    float s = x0 + x1, sq = x0 * x0 + x1 * x1;
    #pragma unroll
    for (int off = 32; off > 0; off >>= 1) {
        s += __shfl_down(s, off);
        sq += __shfl_down(sq, off);
    }
    __shared__ float ps[4], pq[4], pc0[4], pc1[4];
    int wv = t >> 6, lane = t & 63;
    if (lane == 0) { ps[wv] = s; pq[wv] = sq; }
    __syncthreads();
    float S = ps[0] + ps[1] + ps[2] + ps[3];
    float Q = pq[0] + pq[1] + pq[2] + pq[3];
    float mean = S * (1.f / DIM);
    float var = Q * (1.f / DIM) - mean * mean;
    float inv = rsqrtf(var + LN_EPS);
    float xh0 = (x0 - mean) * inv * g[t] + b[t];
    float xh1 = (x1 - mean) * inv * g[t + 256] + b[t + 256];
    float c0 = xh0 * w[t * 2]     + xh1 * w[(t + 256) * 2];
    float c1 = xh0 * w[t * 2 + 1] + xh1 * w[(t + 256) * 2 + 1];
    #pragma unroll
    for (int off = 32; off > 0; off >>= 1) {
        c0 += __shfl_down(c0, off);
        c1 += __shfl_down(c1, off);
    }
    if (lane == 0) { pc0[wv] = c0; pc1[wv] = c1; }
    __syncthreads();
    if (t == 0) {
        out[0] = pc0[0] + pc0[1] + pc0[2] + pc0[3] + fb[0];
        out[1] = pc1[0] + pc1[1] + pc1[2] + pc1[3] + fb[1];
    }
}

// ---------------------------------------------------------------------------
extern "C" void kernel_launch(void* const* d_in, const int* in_sizes, int n_in,
                              void* d_out, int out_size, void* d_ws, size_t ws_size,
                              hipStream_t stream)
{
    const float* h      = (const float*)d_in[0];   // (1,400,1024)
    const float* coords = (const float*)d_in[1];   // (1,400,2)
    const float* fc1_w  = (const float*)d_in[2];   // (1024,512)
    const float* fc1_b  = (const float*)d_in[3];
    const float* cls    = (const float*)d_in[4];   // (1,1,512)
    const float* norm_g = (const float*)d_in[25];
    const float* norm_b = (const float*)d_in[26];
    const float* fc2_w  = (const float*)d_in[27];  // (512,2)
    const float* fc2_b  = (const float*)d_in[28];

    float* ws  = (float*)d_ws;
    float* h0  = ws;                               // (401,512)
    float* xln = h0  + (long)NP * DIM;             // (401,512)
    float* qkv = xln + (long)NP * DIM;             // (401,1536)
    float* att = qkv + (long)NP * 3 * DIM;         // (401,512)
    float* S   = att + (long)NP * DIM;             // (8,NP,SP)
    float* T   = S   + (long)HEADS * PLANE;        // (2,CPB_TROWS,8)

    // fc1 + relu into h0 rows 1..400; CLS into row 0
    gemm_kernel<false><<<dim3(13, 8, 1), 256, 0, stream>>>(
        h, 1024, 0, fc1_w, 512, 0, fc1_b, nullptr, 0, 0,
        h0 + DIM, DIM, 0, 400, DIM, 1024, 1.f, 1);
    cls_kernel<<<1, 128, 0, stream>>>(cls, h0);

    // both layers' angle tables in one launch
    cpb_table_kernel<<<dim3(CPB_M / 64 + 1, 2), 256, 0, stream>>>(
        (const float*)d_in[7],  (const float*)d_in[8],
        (const float*)d_in[9],  (const float*)d_in[10],
        (const float*)d_in[17], (const float*)d_in[18],
        (const float*)d_in[19], (const float*)d_in[20], T);

    for (int l = 0; l < 2; ++l) {
        int base = 5 + 10 * l;
        const float* ng     = (const float*)d_in[base + 0];
        const float* nb     = (const float*)d_in[base + 1];
        const float* qkv_w  = (const float*)d_in[base + 6];
        const float* qkv_b  = (const float*)d_in[base + 7];
        const float* proj_w = (const float*)d_in[base + 8];
        const float* proj_b = (const float*)d_in[base + 9];

        ln_kernel<<<NP, 256, 0, stream>>>(h0, ng, nb, xln);

        gemm_kernel<false><<<dim3(13, 24, 1), 256, 0, stream>>>(
            xln, DIM, 0, qkv_w, 3 * DIM, 0, qkv_b, nullptr, 0, 0,
            qkv, 3 * DIM, 0, NP, 3 * DIM, DIM, 1.f, 0);

        // bias planes -> S (QK^T accumulates on top via resid=S)
        cpb_pairs_kernel<<<(NP * NP + 255) / 256, 256, 0, stream>>>(
            coords, T + (long)l * CPB_TROWS * 8, S);

        gemm_kernel<true><<<dim3(13, 7, HEADS), 256, 0, stream>>>(
            qkv, 3 * DIM, HD,                 // A = q slice
            qkv + DIM, 3 * DIM, HD,           // B = k slice (N x K)
            nullptr, S, SP, (long)PLANE,      // resid = bias planes (in-place)
            S, SP, (long)PLANE,
            NP, NP, HD, ATT_SCALE, 0);

        softmax_kernel<<<dim3(NP, HEADS), 256, 0, stream>>>(S);

        gemm_kernel<false><<<dim3(13, 1, HEADS), 256, 0, stream>>>(
            S, SP, (long)PLANE,
            qkv + 2 * DIM, 3 * DIM, HD,
            nullptr, nullptr, 0, 0,
            att, DIM, HD,
            NP, HD, NP, 1.f, 0);

        gemm_kernel<false><<<dim3(13, 8, 1), 256, 0, stream>>>(
            att, DIM, 0, proj_w, DIM, 0, proj_b, h0, DIM, 0,
            h0, DIM, 0, NP, DIM, DIM, 1.f, 0);
    }

    final_kernel<<<1, 256, 0, stream>>>(h0, norm_g, norm_b, fc2_w, fc2_b,
                                        (float*)d_out);
}

// Round 4
// 303.763 us; speedup vs baseline: 2.4016x; 1.1885x over previous
//
#include <hip/hip_runtime.h>
#include <math.h>

#define NP 401          // tokens incl. CLS (400 patches, side=20, add=0)
#define DIM 512
#define HEADS 8
#define HD 64
#define CPBH 512
#define LN_EPS 1e-5f
#define ATT_SCALE 0.125f  // 64^-0.5
#define SP 416            // padded row stride for S planes (16B-aligned)
#define PLANE (NP * SP)   // floats per head plane
#define CPB_M 16384       // angle-table resolution
#define CPB_TROWS (CPB_M + 64)   // + zero-vector entry block

// ---------------------------------------------------------------------------
// Tiled GEMM with optional split-K.
//   TM=32, TN=64, KT=16, 256 threads, 2x4 micro-tile, register double-buffer.
//   blockIdx.z = batch * skN + sk. Each sk covers K-slice [sk*KS,(sk+1)*KS).
//   skN==1: full epilogue (scale, bias, resid, relu).
//   skN>1 : writes scale*partial to C + batch*cBatch + sk*cSlice (reduce
//           kernel applies bias/resid/relu afterwards).
//   TRANSB=false: B is K x N;  TRANSB=true: B is N x K -> C = A @ B^T
// ---------------------------------------------------------------------------
template<bool TRANSB>
__global__ __launch_bounds__(256) void gemm_kernel(
    const float* __restrict__ A, int lda, long aBatch,
    const float* __restrict__ B, int ldb, long bBatch,
    const float* __restrict__ bias,
    const float* __restrict__ resid, int ldr, long rBatch,
    float* __restrict__ C, int ldc, long cBatch, long cSlice,
    int M, int N, int K, float scale, int doRelu, int skN)
{
    __shared__ float as[16][34];   // [k][m]
    __shared__ float bs[16][68];   // [k][n]
    const int z = blockIdx.z;
    const int batch = z / skN;
    const int sk = z - batch * skN;
    A += batch * aBatch;
    B += batch * bBatch;
    C += batch * cBatch + (long)sk * cSlice;
    const float* res = resid ? resid + batch * rBatch : nullptr;
    const int KS = ((K + skN * 16 - 1) / (skN * 16)) * 16;
    const int kBeg = sk * KS;
    const int kEnd = (kBeg + KS < K) ? kBeg + KS : K;

    const int m0 = blockIdx.x * 32, n0 = blockIdx.y * 64;
    const int tid = threadIdx.x;
    const int tx = tid & 15;      // n-quad
    const int ty = tid >> 4;      // m-pair

    const int arow = tid >> 2, aq = tid & 3;
    const int bk = tid >> 4, bnq = tid & 15;
    const int brow = tid >> 2, bq = tid & 3;

    float acc[2][4] = {{0.f,0.f,0.f,0.f},{0.f,0.f,0.f,0.f}};
    float aR[4] = {0.f,0.f,0.f,0.f};
    float bR[4] = {0.f,0.f,0.f,0.f};

    auto loadA = [&](int k0, float r[4]) {
        r[0] = r[1] = r[2] = r[3] = 0.f;
        if (tid < 128) {
            int gm = m0 + arow;
            if (gm < M) {
                int gk = k0 + aq * 4;
                const float* p = A + (long)gm * lda + gk;
                if (gk + 3 < kEnd) {
                    float4 v = *(const float4*)p;
                    r[0] = v.x; r[1] = v.y; r[2] = v.z; r[3] = v.w;
                } else {
                    if (gk     < kEnd) r[0] = p[0];
                    if (gk + 1 < kEnd) r[1] = p[1];
                    if (gk + 2 < kEnd) r[2] = p[2];
                    if (gk + 3 < kEnd) r[3] = p[3];
                }
            }
        }
    };
    auto loadB = [&](int k0, float r[4]) {
        r[0] = r[1] = r[2] = r[3] = 0.f;
        if (!TRANSB) {
            int gk = k0 + bk;
            if (gk < kEnd) {
                int gn = n0 + bnq * 4;
                const float* p = B + (long)gk * ldb + gn;
                if (gn + 3 < N) {
                    float4 v = *(const float4*)p;
                    r[0] = v.x; r[1] = v.y; r[2] = v.z; r[3] = v.w;
                } else {
                    if (gn     < N) r[0] = p[0];
                    if (gn + 1 < N) r[1] = p[1];
                    if (gn + 2 < N) r[2] = p[2];
                    if (gn + 3 < N) r[3] = p[3];
                }
            }
        } else {
            int gn = n0 + brow;
            if (gn < N) {
                int gk = k0 + bq * 4;
                const float* p = B + (long)gn * ldb + gk;
                if (gk + 3 < kEnd) {
                    float4 v = *(const float4*)p;
                    r[0] = v.x; r[1] = v.y; r[2] = v.z; r[3] = v.w;
                } else {
                    if (gk     < kEnd) r[0] = p[0];
                    if (gk + 1 < kEnd) r[1] = p[1];
                    if (gk + 2 < kEnd) r[2] = p[2];
                    if (gk + 3 < kEnd) r[3] = p[3];
                }
            }
        }
    };

    loadA(kBeg, aR);
    loadB(kBeg, bR);

    for (int k0 = kBeg; k0 < kEnd; k0 += 16) {
        if (tid < 128) {
            as[aq * 4 + 0][arow] = aR[0];
            as[aq * 4 + 1][arow] = aR[1];
            as[aq * 4 + 2][arow] = aR[2];
            as[aq * 4 + 3][arow] = aR[3];
        }
        if (!TRANSB) {
            *(float4*)&bs[bk][bnq * 4] = make_float4(bR[0], bR[1], bR[2], bR[3]);
        } else {
            bs[bq * 4 + 0][brow] = bR[0];
            bs[bq * 4 + 1][brow] = bR[1];
            bs[bq * 4 + 2][brow] = bR[2];
            bs[bq * 4 + 3][brow] = bR[3];
        }
        __syncthreads();

        float nA[4] = {0.f,0.f,0.f,0.f};
        float nB[4] = {0.f,0.f,0.f,0.f};
        if (k0 + 16 < kEnd) {
            loadA(k0 + 16, nA);
            loadB(k0 + 16, nB);
        }

        #pragma unroll
        for (int kk = 0; kk < 16; ++kk) {
            float2 a2 = *(const float2*)&as[kk][ty * 2];
            float4 b4 = *(const float4*)&bs[kk][tx * 4];
            acc[0][0] = fmaf(a2.x, b4.x, acc[0][0]);
            acc[0][1] = fmaf(a2.x, b4.y, acc[0][1]);
            acc[0][2] = fmaf(a2.x, b4.z, acc[0][2]);
            acc[0][3] = fmaf(a2.x, b4.w, acc[0][3]);
            acc[1][0] = fmaf(a2.y, b4.x, acc[1][0]);
            acc[1][1] = fmaf(a2.y, b4.y, acc[1][1]);
            acc[1][2] = fmaf(a2.y, b4.z, acc[1][2]);
            acc[1][3] = fmaf(a2.y, b4.w, acc[1][3]);
        }
        __syncthreads();

        aR[0] = nA[0]; aR[1] = nA[1]; aR[2] = nA[2]; aR[3] = nA[3];
        bR[0] = nB[0]; bR[1] = nB[1]; bR[2] = nB[2]; bR[3] = nB[3];
    }

    #pragma unroll
    for (int r = 0; r < 2; ++r) {
        int m = m0 + ty * 2 + r;
        if (m >= M) continue;
        #pragma unroll
        for (int c = 0; c < 4; ++c) {
            int n = n0 + tx * 4 + c;
            if (n >= N) continue;
            float v = acc[r][c] * scale;
            if (skN == 1) {
                if (bias) v += bias[n];
                if (res)  v += res[(long)m * ldr + n];
                if (doRelu) v = fmaxf(v, 0.f);
            }
            C[(long)m * ldc + n] = v;
        }
    }
}

// ---------------------------------------------------------------------------
// Split-K reduce + epilogue: out[i] = epi(sum_sk P[sk][i] + bias + resid).
// Dense layouts (out ld == N). float4 per thread.
// ---------------------------------------------------------------------------
__global__ __launch_bounds__(256) void reduce_kernel(
    const float* __restrict__ P, long slice, int skN,
    const float* __restrict__ bias, const float* __restrict__ resid,
    float* __restrict__ out, int total, int N, int doRelu)
{
    int idx = (blockIdx.x * 256 + threadIdx.x) * 4;
    if (idx >= total) return;
    float4 s = *(const float4*)(P + idx);
    for (int k = 1; k < skN; ++k) {
        float4 p = *(const float4*)(P + (long)k * slice + idx);
        s.x += p.x; s.y += p.y; s.z += p.z; s.w += p.w;
    }
    if (bias) {
        const float4 b = *(const float4*)(bias + (idx % N));
        s.x += b.x; s.y += b.y; s.z += b.z; s.w += b.w;
    }
    if (resid) {
        const float4 r = *(const float4*)(resid + idx);
        s.x += r.x; s.y += r.y; s.z += r.z; s.w += r.w;
    }
    if (doRelu) {
        s.x = fmaxf(s.x, 0.f); s.y = fmaxf(s.y, 0.f);
        s.z = fmaxf(s.z, 0.f); s.w = fmaxf(s.w, 0.f);
    }
    *(float4*)(out + idx) = s;
}

// ---------------------------------------------------------------------------
// CPB angle table (bias depends only on pair direction). See round-3 notes.
// ---------------------------------------------------------------------------
__global__ __launch_bounds__(256) void cpb_table_kernel(
    const float* __restrict__ w1_0, const float* __restrict__ b1_0,
    const float* __restrict__ w2_0, const float* __restrict__ b2_0,
    const float* __restrict__ w1_1, const float* __restrict__ b1_1,
    const float* __restrict__ w2_1, const float* __restrict__ b2_1,
    float* __restrict__ T)            // (2, CPB_TROWS, 8)
{
    const int z = blockIdx.y;
    const float* __restrict__ w1 = z ? w1_1 : w1_0;
    const float* __restrict__ b1 = z ? b1_1 : b1_0;
    const float* __restrict__ w2 = z ? w2_1 : w2_0;
    const float* __restrict__ b2 = z ? b2_1 : b2_0;

    const int lane = threadIdx.x & 63;
    const int wv = threadIdx.x >> 6;
    const int a = blockIdx.x * 64 + lane;

    float ca = 0.f, sa = 0.f;
    if (blockIdx.x != CPB_M / 64) {
        float th = fmaf((float)a, (float)(2.0 * M_PI / CPB_M), -(float)M_PI);
        sincosf(th, &sa, &ca);
    }

    float acc[8] = {};
    const int kbeg = wv * 128;
    #pragma unroll 4
    for (int k = kbeg; k < kbeg + 128; ++k) {
        float hk = fmaxf(fmaf(ca, w1[k], fmaf(sa, w1[CPBH + k], b1[k])), 0.f);
        #pragma unroll
        for (int h = 0; h < 8; ++h)
            acc[h] = fmaf(hk, w2[k * 8 + h], acc[h]);
    }

    __shared__ float red[4][64][8];
    #pragma unroll
    for (int h = 0; h < 8; ++h) red[wv][lane][h] = acc[h];
    __syncthreads();
    if (threadIdx.x < 64) {
        int t = threadIdx.x;
        float* out = T + ((long)z * CPB_TROWS + blockIdx.x * 64 + t) * 8;
        #pragma unroll
        for (int h = 0; h < 8; ++h)
            out[h] = red[0][t][h] + red[1][t][h] + red[2][t][h] + red[3][t][h]
                     + b2[h];
    }
}

// ---------------------------------------------------------------------------
// Expand per-pair bias from the angle table (linear interp) into S planes.
// ---------------------------------------------------------------------------
__global__ __launch_bounds__(256) void cpb_pairs_kernel(
    const float* __restrict__ coords,   // (400,2); token 0 = CLS at (0,0)
    const float* __restrict__ T,        // this layer's (CPB_TROWS, 8) table
    float* __restrict__ S)              // (8, NP, SP)
{
    int p = blockIdx.x * 256 + threadIdx.x;
    if (p >= NP * NP) return;
    int i = p / NP, j = p - i * NP;
    float xi = (i == 0) ? 0.f : coords[(i - 1) * 2];
    float yi = (i == 0) ? 0.f : coords[(i - 1) * 2 + 1];
    float xj = (j == 0) ? 0.f : coords[(j - 1) * 2];
    float yj = (j == 0) ? 0.f : coords[(j - 1) * 2 + 1];
    float rx = xi - xj, ry = yi - yj;

    int m, m2;
    float frac;
    if (rx == 0.f && ry == 0.f) {
        m = CPB_M; m2 = CPB_M; frac = 0.f;     // zero-vector entry
    } else {
        float x = (atan2f(ry, rx) + 3.14159265358979f)
                  * (float)(CPB_M / (2.0 * M_PI));
        int mi = (int)x;
        frac = x - (float)mi;
        m = (mi >= CPB_M) ? mi - CPB_M : mi;
        m2 = (m + 1 >= CPB_M) ? 0 : m + 1;
    }
    float4 a0 = *(const float4*)(T + (long)m * 8);
    float4 a1 = *(const float4*)(T + (long)m * 8 + 4);
    float4 c0 = *(const float4*)(T + (long)m2 * 8);
    float4 c1 = *(const float4*)(T + (long)m2 * 8 + 4);

    long base = (long)i * SP + j;
    S[0L * PLANE + base] = fmaf(frac, c0.x - a0.x, a0.x);
    S[1L * PLANE + base] = fmaf(frac, c0.y - a0.y, a0.y);
    S[2L * PLANE + base] = fmaf(frac, c0.z - a0.z, a0.z);
    S[3L * PLANE + base] = fmaf(frac, c0.w - a0.w, a0.w);
    S[4L * PLANE + base] = fmaf(frac, c1.x - a1.x, a1.x);
    S[5L * PLANE + base] = fmaf(frac, c1.y - a1.y, a1.y);
    S[6L * PLANE + base] = fmaf(frac, c1.z - a1.z, a1.z);
    S[7L * PLANE + base] = fmaf(frac, c1.w - a1.w, a1.w);
}

// ---------------------------------------------------------------------------
// LayerNorm over DIM=512, one block (256 thr) per row.
// ---------------------------------------------------------------------------
__global__ __launch_bounds__(256) void ln_kernel(
    const float* __restrict__ x, const float* __restrict__ g,
    const float* __restrict__ b, float* __restrict__ y)
{
    int r = blockIdx.x, t = threadIdx.x;
    const float* xr = x + (long)r * DIM;
    float x0 = xr[t], x1 = xr[t + 256];
    float s = x0 + x1, sq = x0 * x0 + x1 * x1;
    #pragma unroll
    for (int off = 32; off > 0; off >>= 1) {
        s += __shfl_down(s, off);
        sq += __shfl_down(sq, off);
    }
    __shared__ float ps[4], pq[4];
    int w = t >> 6, lane = t & 63;
    if (lane == 0) { ps[w] = s; pq[w] = sq; }
    __syncthreads();
    float S = ps[0] + ps[1] + ps[2] + ps[3];
    float Q = pq[0] + pq[1] + pq[2] + pq[3];
    float mean = S * (1.f / DIM);
    float var = Q * (1.f / DIM) - mean * mean;
    float inv = rsqrtf(var + LN_EPS);
    float* yr = y + (long)r * DIM;
    yr[t]       = (x0 - mean) * inv * g[t] + b[t];
    yr[t + 256] = (x1 - mean) * inv * g[t + 256] + b[t + 256];
}

// ---------------------------------------------------------------------------
// Softmax over last axis of S (8, NP, SP) rows of 401, in place.
// ---------------------------------------------------------------------------
__global__ __launch_bounds__(256) void softmax_kernel(float* __restrict__ S)
{
    long base = (long)blockIdx.y * PLANE + (long)blockIdx.x * SP;
    int t = threadIdx.x;
    float v0 = (t < NP) ? S[base + t] : -INFINITY;
    float v1 = (t + 256 < NP) ? S[base + t + 256] : -INFINITY;
    float m = fmaxf(v0, v1);
    #pragma unroll
    for (int off = 32; off > 0; off >>= 1) m = fmaxf(m, __shfl_down(m, off));
    __shared__ float pm[4], psum[4];
    int w = t >> 6, lane = t & 63;
    if (lane == 0) pm[w] = m;
    __syncthreads();
    float M4 = fmaxf(fmaxf(pm[0], pm[1]), fmaxf(pm[2], pm[3]));
    float e0 = (t < NP) ? __expf(v0 - M4) : 0.f;
    float e1 = (t + 256 < NP) ? __expf(v1 - M4) : 0.f;
    float s = e0 + e1;
    #pragma unroll
    for (int off = 32; off > 0; off >>= 1) s += __shfl_down(s, off);
    if (lane == 0) psum[w] = s;
    __syncthreads();
    float inv = 1.f / (psum[0] + psum[1] + psum[2] + psum[3]);
    if (t < NP)       S[base + t] = e0 * inv;
    if (t + 256 < NP) S[base + t + 256] = e1 * inv;
}

// CLS token -> row 0 of h0
__global__ void cls_kernel(const float* __restrict__ cls, float* __restrict__ h0)
{
    ((float4*)h0)[threadIdx.x] = ((const float4*)cls)[threadIdx.x];
}

// Final: LN(h0 row 0) @ fc2_w + fc2_b -> out[2]
__global__ __launch_bounds__(256) void final_kernel(
    const float* __restrict__ h0, const float* __restrict__ g,
    const float* __restrict__ b, const float* __restrict__ w,
    const float* __restrict__ fb, float* __restrict__ out)
{
    int t = threadIdx.x;
    float x0 = h0[t], x1 = h0[t + 256];
    float s = x0 + x1, sq = x0 * x0 + x1 * x1;
    #pragma unroll
    for (int off = 32; off > 0; off >>= 1) {
        s += __shfl_down(s, off);
        sq += __shfl_down(sq, off);
    }
    __shared__ float ps[4], pq[4], pc0[4], pc1[4];
    int wv = t >> 6, lane = t & 63;
    if (lane == 0) { ps[wv] = s; pq[wv] = sq; }
    __syncthreads();
    float S = ps[0] + ps[1] + ps[2] + ps[3];
    float Q = pq[0] + pq[1] + pq[2] + pq[3];
    float mean = S * (1.f / DIM);
    float var = Q * (1.f / DIM) - mean * mean;
    float inv = rsqrtf(var + LN_EPS);
    float xh0 = (x0 - mean) * inv * g[t] + b[t];
    float xh1 = (x1 - mean) * inv * g[t + 256] + b[t + 256];
    float c0 = xh0 * w[t * 2]     + xh1 * w[(t + 256) * 2];
    float c1 = xh0 * w[t * 2 + 1] + xh1 * w[(t + 256) * 2 + 1];
    #pragma unroll
    for (int off = 32; off > 0; off >>= 1) {
        c0 += __shfl_down(c0, off);
        c1 += __shfl_down(c1, off);
    }
    if (lane == 0) { pc0[wv] = c0; pc1[wv] = c1; }
    __syncthreads();
    if (t == 0) {
        out[0] = pc0[0] + pc0[1] + pc0[2] + pc0[3] + fb[0];
        out[1] = pc1[0] + pc1[1] + pc1[2] + pc1[3] + fb[1];
    }
}

// ---------------------------------------------------------------------------
extern "C" void kernel_launch(void* const* d_in, const int* in_sizes, int n_in,
                              void* d_out, int out_size, void* d_ws, size_t ws_size,
                              hipStream_t stream)
{
    const float* h      = (const float*)d_in[0];   // (1,400,1024)
    const float* coords = (const float*)d_in[1];   // (1,400,2)
    const float* fc1_w  = (const float*)d_in[2];   // (1024,512)
    const float* fc1_b  = (const float*)d_in[3];
    const float* cls    = (const float*)d_in[4];   // (1,1,512)
    const float* norm_g = (const float*)d_in[25];
    const float* norm_b = (const float*)d_in[26];
    const float* fc2_w  = (const float*)d_in[27];  // (512,2)
    const float* fc2_b  = (const float*)d_in[28];

    float* ws  = (float*)d_ws;
    float* h0  = ws;                               // (401,512)
    float* xln = h0  + (long)NP * DIM;             // (401,512)
    float* qkv = xln + (long)NP * DIM;             // (401,1536)
    float* att = qkv + (long)NP * 3 * DIM;         // (401,512)
    float* S   = att + (long)NP * DIM;             // (8,NP,SP); doubles as qkv-partial scratch
    float* T   = S   + (long)HEADS * PLANE;        // (2,CPB_TROWS,8)
    float* P   = T   + 2L * CPB_TROWS * 8;         // (4,401,512) partials (fc1/pv/proj)

    // fc1 + relu into h0 rows 1..400 (split-K 4); CLS into row 0
    gemm_kernel<false><<<dim3(13, 8, 4), 256, 0, stream>>>(
        h, 1024, 0, fc1_w, 512, 0, nullptr, nullptr, 0, 0,
        P, 512, 0, 400L * 512, 400, DIM, 1024, 1.f, 0, 4);
    cls_kernel<<<1, 128, 0, stream>>>(cls, h0);
    // both layers' angle tables (independent of fc1)
    cpb_table_kernel<<<dim3(CPB_M / 64 + 1, 2), 256, 0, stream>>>(
        (const float*)d_in[7],  (const float*)d_in[8],
        (const float*)d_in[9],  (const float*)d_in[10],
        (const float*)d_in[17], (const float*)d_in[18],
        (const float*)d_in[19], (const float*)d_in[20], T);
    reduce_kernel<<<200, 256, 0, stream>>>(
        P, 400L * 512, 4, fc1_b, nullptr, h0 + DIM, 400 * 512, 512, 1);

    for (int l = 0; l < 2; ++l) {
        int base = 5 + 10 * l;
        const float* ng     = (const float*)d_in[base + 0];
        const float* nb     = (const float*)d_in[base + 1];
        const float* qkv_w  = (const float*)d_in[base + 6];
        const float* qkv_b  = (const float*)d_in[base + 7];
        const float* proj_w = (const float*)d_in[base + 8];
        const float* proj_b = (const float*)d_in[base + 9];

        ln_kernel<<<NP, 256, 0, stream>>>(h0, ng, nb, xln);

        // qkv GEMM split-K 2; partials alias S (dead until pairs runs)
        gemm_kernel<false><<<dim3(13, 24, 2), 256, 0, stream>>>(
            xln, DIM, 0, qkv_w, 3 * DIM, 0, nullptr, nullptr, 0, 0,
            S, 3 * DIM, 0, (long)NP * 3 * DIM, NP, 3 * DIM, DIM, 1.f, 0, 2);
        reduce_kernel<<<602, 256, 0, stream>>>(
            S, (long)NP * 3 * DIM, 2, qkv_b, nullptr, qkv,
            NP * 3 * DIM, 3 * DIM, 0);

        // bias planes -> S (QK^T accumulates on top via resid=S)
        cpb_pairs_kernel<<<(NP * NP + 255) / 256, 256, 0, stream>>>(
            coords, T + (long)l * CPB_TROWS * 8, S);

        gemm_kernel<true><<<dim3(13, 7, HEADS), 256, 0, stream>>>(
            qkv, 3 * DIM, HD,                 // A = q slice
            qkv + DIM, 3 * DIM, HD,           // B = k slice (N x K)
            nullptr, S, SP, (long)PLANE,      // resid = bias planes (in-place)
            S, SP, (long)PLANE, 0,
            NP, NP, HD, ATT_SCALE, 0, 1);

        softmax_kernel<<<dim3(NP, HEADS), 256, 0, stream>>>(S);

        // att = P @ v, all heads, split-K 4 -> partials (4,401,512)
        gemm_kernel<false><<<dim3(13, 1, 32), 256, 0, stream>>>(
            S, SP, (long)PLANE,
            qkv + 2 * DIM, 3 * DIM, HD,
            nullptr, nullptr, 0, 0,
            P, 512, HD, 401L * 512,
            NP, HD, NP, 1.f, 0, 4);
        reduce_kernel<<<201, 256, 0, stream>>>(
            P, 401L * 512, 4, nullptr, nullptr, att, NP * DIM, 512, 0);

        // h0 += att @ proj_w + proj_b, split-K 4
        gemm_kernel<false><<<dim3(13, 8, 4), 256, 0, stream>>>(
            att, DIM, 0, proj_w, DIM, 0, nullptr, nullptr, 0, 0,
            P, 512, 0, 401L * 512, NP, DIM, DIM, 1.f, 0, 4);
        reduce_kernel<<<201, 256, 0, stream>>>(
            P, 401L * 512, 4, proj_b, h0, h0, NP * DIM, 512, 0);
    }

    final_kernel<<<1, 256, 0, stream>>>(h0, norm_g, norm_b, fc2_w, fc2_b,
                                        (float*)d_out);
}

// Round 5
// 282.157 us; speedup vs baseline: 2.5855x; 1.0766x over previous
//
#include <hip/hip_runtime.h>
#include <math.h>

#define NP 401            // tokens incl. CLS (400 patches, side=20, add=0)
#define DIM 512
#define HEADS 8
#define HD 64
#define LN_EPS 1e-5f
#define ATT_SCALE 0.125f
#define SP 448            // S plane row stride (7 x 64)
#define PLANE (NP * SP)
#define CPB_M 16384       // angle-table resolution
#define TSTRIDE (CPB_M + 64)   // per (layer,head) plane stride
#define PS (401L * 1536)  // qkv partial slice

// ---------------------------------------------------------------------------
// 64x64-tile GEMM body: 256 thr, 4x4 micro-tile, K-chunk 16, register
// double-buffered staging via caller-supplied loaders.
// loadA(k0, r[4]): thread's 4 staged A elems: rows m0+(tid>>2), k=k0+(tid&3)*4+j
// loadB(k0, r[4]): TB=false: k=k0+(tid>>4), n=n0+(tid&15)*4+j (row-major B)
//                  TB=true : rows n0+(tid>>2), k=k0+(tid&3)*4+j (B^T staging)
// ---------------------------------------------------------------------------
template<bool TB, typename LA, typename LB>
__device__ __forceinline__ void gemm64(
    int kBeg, int kEnd, int tid,
    float (*as)[68], float (*bs)[68], float (&acc)[4][4],
    LA&& loadA, LB&& loadB)
{
    float aR[4], bR[4];
    loadA(kBeg, aR);
    loadB(kBeg, bR);
    for (int k0 = kBeg; k0 < kEnd; k0 += 16) {
        const int arow = tid >> 2, aq = tid & 3;
        as[aq * 4 + 0][arow] = aR[0];
        as[aq * 4 + 1][arow] = aR[1];
        as[aq * 4 + 2][arow] = aR[2];
        as[aq * 4 + 3][arow] = aR[3];
        if (!TB) {
            *(float4*)&bs[tid >> 4][(tid & 15) * 4] =
                make_float4(bR[0], bR[1], bR[2], bR[3]);
        } else {
            bs[aq * 4 + 0][arow] = bR[0];
            bs[aq * 4 + 1][arow] = bR[1];
            bs[aq * 4 + 2][arow] = bR[2];
            bs[aq * 4 + 3][arow] = bR[3];
        }
        __syncthreads();
        float nA[4] = {0.f,0.f,0.f,0.f}, nB[4] = {0.f,0.f,0.f,0.f};
        if (k0 + 16 < kEnd) { loadA(k0 + 16, nA); loadB(k0 + 16, nB); }
        const int tx = tid & 15, ty = tid >> 4;
        #pragma unroll
        for (int kk = 0; kk < 16; ++kk) {
            float4 a4 = *(const float4*)&as[kk][ty * 4];
            float4 b4 = *(const float4*)&bs[kk][tx * 4];
            float av[4] = {a4.x, a4.y, a4.z, a4.w};
            float bv[4] = {b4.x, b4.y, b4.z, b4.w};
            #pragma unroll
            for (int r = 0; r < 4; ++r)
                #pragma unroll
                for (int c = 0; c < 4; ++c)
                    acc[r][c] = fmaf(av[r], bv[c], acc[r][c]);
        }
        __syncthreads();
        #pragma unroll
        for (int j = 0; j < 4; ++j) { aR[j] = nA[j]; bR[j] = nB[j]; }
    }
}

// ---------------------------------------------------------------------------
// Generic split-K GEMM: P[sk] = A[:, slice] @ B[slice, :]  (raw partials)
// ---------------------------------------------------------------------------
__global__ __launch_bounds__(256) void gemm_split_kernel(
    const float* __restrict__ A, int lda,
    const float* __restrict__ B, int ldb,
    float* __restrict__ P, int ldc, long slice,
    int M, int N, int K, int skN)
{
    __shared__ float as[16][68], bs[16][68];
    const int tid = threadIdx.x;
    const int m0 = blockIdx.x * 64, n0 = blockIdx.y * 64;
    const int sk = blockIdx.z;
    const int KS = ((K + skN * 16 - 1) / (skN * 16)) * 16;
    const int kBeg = sk * KS;
    const int kEnd = (kBeg + KS < K) ? kBeg + KS : K;
    float acc[4][4] = {};

    auto loadA = [&](int k0, float r[4]) {
        r[0] = r[1] = r[2] = r[3] = 0.f;
        int gm = m0 + (tid >> 2);
        if (gm >= M) return;
        int gk = k0 + (tid & 3) * 4;
        const float* p = A + (long)gm * lda + gk;
        if (gk + 3 < kEnd) {
            float4 v = *(const float4*)p;
            r[0] = v.x; r[1] = v.y; r[2] = v.z; r[3] = v.w;
        } else {
            #pragma unroll
            for (int j = 0; j < 4; ++j) if (gk + j < kEnd) r[j] = p[j];
        }
    };
    auto loadB = [&](int k0, float r[4]) {
        r[0] = r[1] = r[2] = r[3] = 0.f;
        int gk = k0 + (tid >> 4);
        if (gk >= kEnd) return;
        int gn = n0 + (tid & 15) * 4;
        const float* p = B + (long)gk * ldb + gn;
        if (gn + 3 < N) {
            float4 v = *(const float4*)p;
            r[0] = v.x; r[1] = v.y; r[2] = v.z; r[3] = v.w;
        } else {
            #pragma unroll
            for (int j = 0; j < 4; ++j) if (gn + j < N) r[j] = p[j];
        }
    };
    if (kBeg < kEnd)
        gemm64<false>(kBeg, kEnd, tid, as, bs, acc, loadA, loadB);

    float* C = P + (long)sk * slice;
    const int tx = tid & 15, ty = tid >> 4;
    #pragma unroll
    for (int r = 0; r < 4; ++r) {
        int m = m0 + ty * 4 + r;
        if (m >= M) continue;
        int n = n0 + tx * 4;
        if (n + 3 < N) {
            *(float4*)&C[(long)m * ldc + n] =
                make_float4(acc[r][0], acc[r][1], acc[r][2], acc[r][3]);
        } else {
            #pragma unroll
            for (int c = 0; c < 4; ++c)
                if (n + c < N) C[(long)m * ldc + n + c] = acc[r][c];
        }
    }
}

// ---------------------------------------------------------------------------
// QK^T with fused qkv-partial-sum + bias staging and fused CPB-bias epilogue.
// grid (7, 7, 8): m0, n0, head. S[h][i][j] = 0.125*q_i.k_j + bias(h,i,j)
// ---------------------------------------------------------------------------
__global__ __launch_bounds__(256) void qk_kernel(
    const float* __restrict__ Pq, const float* __restrict__ qkv_b,
    const int* __restrict__ pm, const float* __restrict__ pf,
    const float* __restrict__ T,        // this layer: 8 planes, stride TSTRIDE
    float* __restrict__ S)
{
    __shared__ float as[16][68], bs[16][68];
    const int tid = threadIdx.x;
    const int m0 = blockIdx.x * 64, n0 = blockIdx.y * 64, h = blockIdx.z;
    float acc[4][4] = {};

    auto loadQ = [&](int k0, float r[4]) {
        int gm = m0 + (tid >> 2);
        if (gm > 400) { r[0]=r[1]=r[2]=r[3]=0.f; return; }
        int gk = k0 + (tid & 3) * 4;
        long off = (long)gm * 1536 + h * 64 + gk;
        float4 x = *(const float4*)(Pq + off);
        float4 y = *(const float4*)(Pq + PS + off);
        float4 b = *(const float4*)(qkv_b + h * 64 + gk);
        r[0] = x.x + y.x + b.x; r[1] = x.y + y.y + b.y;
        r[2] = x.z + y.z + b.z; r[3] = x.w + y.w + b.w;
    };
    auto loadK = [&](int k0, float r[4]) {
        int gn = n0 + (tid >> 2);
        if (gn > 400) { r[0]=r[1]=r[2]=r[3]=0.f; return; }
        int gk = k0 + (tid & 3) * 4;
        long off = (long)gn * 1536 + 512 + h * 64 + gk;
        float4 x = *(const float4*)(Pq + off);
        float4 y = *(const float4*)(Pq + PS + off);
        float4 b = *(const float4*)(qkv_b + 512 + h * 64 + gk);
        r[0] = x.x + y.x + b.x; r[1] = x.y + y.y + b.y;
        r[2] = x.z + y.z + b.z; r[3] = x.w + y.w + b.w;
    };
    gemm64<true>(0, 64, tid, as, bs, acc, loadQ, loadK);

    const int tx = tid & 15, ty = tid >> 4;
    const float* Tt = T + (long)h * TSTRIDE;
    float* Sp = S + (long)h * PLANE;
    #pragma unroll
    for (int r = 0; r < 4; ++r) {
        int i = m0 + ty * 4 + r;
        if (i > 400) continue;
        #pragma unroll
        for (int c = 0; c < 4; ++c) {
            int j = n0 + tx * 4 + c;
            if (j > 400) continue;
            int id = i * 416 + j;
            int mm = pm[id];
            float fr = pf[id];
            float t0 = Tt[mm], t1 = Tt[mm + 1];
            Sp[(long)i * SP + j] =
                fmaf(acc[r][c], ATT_SCALE, fmaf(fr, t1 - t0, t0));
        }
    }
}

// ---------------------------------------------------------------------------
// PV with fused qkv-partial-sum + bias on V. Split-K over keys (8 slices).
// grid (7, 1, 64): z = head*8 + sk. Writes raw partials Pv[sk].
// ---------------------------------------------------------------------------
__global__ __launch_bounds__(256) void pv_kernel(
    const float* __restrict__ S, const float* __restrict__ Pq,
    const float* __restrict__ qkv_b, float* __restrict__ Pv)
{
    __shared__ float as[16][68], bs[16][68];
    const int tid = threadIdx.x;
    const int m0 = blockIdx.x * 64;
    const int h = blockIdx.z >> 3, sk = blockIdx.z & 7;
    const int kBeg = sk * 64;
    const int kEnd = (kBeg + 64 < NP) ? kBeg + 64 : NP;
    float acc[4][4] = {};

    auto loadA = [&](int k0, float r[4]) {
        r[0] = r[1] = r[2] = r[3] = 0.f;
        int gm = m0 + (tid >> 2);
        if (gm > 400) return;
        int gk = k0 + (tid & 3) * 4;
        const float* p = S + (long)h * PLANE + (long)gm * SP + gk;
        if (gk + 3 < kEnd) {
            float4 v = *(const float4*)p;
            r[0] = v.x; r[1] = v.y; r[2] = v.z; r[3] = v.w;
        } else {
            #pragma unroll
            for (int j = 0; j < 4; ++j) if (gk + j < kEnd) r[j] = p[j];
        }
    };
    auto loadB = [&](int k0, float r[4]) {
        r[0] = r[1] = r[2] = r[3] = 0.f;
        int key = k0 + (tid >> 4);
        if (key >= kEnd) return;
        int d = (tid & 15) * 4;
        long off = (long)key * 1536 + 1024 + h * 64 + d;
        float4 x = *(const float4*)(Pq + off);
        float4 y = *(const float4*)(Pq + PS + off);
        float4 b = *(const float4*)(qkv_b + 1024 + h * 64 + d);
        r[0] = x.x + y.x + b.x; r[1] = x.y + y.y + b.y;
        r[2] = x.z + y.z + b.z; r[3] = x.w + y.w + b.w;
    };
    if (kBeg < kEnd)
        gemm64<false>(kBeg, kEnd, tid, as, bs, acc, loadA, loadB);

    float* C = Pv + (long)sk * (401L * 512);
    const int tx = tid & 15, ty = tid >> 4;
    #pragma unroll
    for (int r = 0; r < 4; ++r) {
        int m = m0 + ty * 4 + r;
        if (m > 400) continue;
        *(float4*)&C[(long)m * 512 + h * 64 + tx * 4] =
            make_float4(acc[r][0], acc[r][1], acc[r][2], acc[r][3]);
    }
}

// Sum the 8 PV partial slices -> att (401,512)
__global__ __launch_bounds__(256) void att_reduce_kernel(
    const float* __restrict__ Pv, float* __restrict__ att)
{
    int idx = (blockIdx.x * 256 + threadIdx.x) * 4;
    if (idx >= 401 * 512) return;
    float4 s = *(const float4*)(Pv + idx);
    #pragma unroll
    for (int k = 1; k < 8; ++k) {
        float4 p = *(const float4*)(Pv + (long)k * 401 * 512 + idx);
        s.x += p.x; s.y += p.y; s.z += p.z; s.w += p.w;
    }
    *(float4*)(att + idx) = s;
}

// ---------------------------------------------------------------------------
// Softmax over rows of S (8, NP, SP), in place. blockIdx: (i, h)
// ---------------------------------------------------------------------------
__global__ __launch_bounds__(256) void softmax_kernel(float* __restrict__ S)
{
    long base = (long)blockIdx.y * PLANE + (long)blockIdx.x * SP;
    int t = threadIdx.x;
    float v0 = (t < NP) ? S[base + t] : -INFINITY;
    float v1 = (t + 256 < NP) ? S[base + t + 256] : -INFINITY;
    float m = fmaxf(v0, v1);
    #pragma unroll
    for (int off = 32; off > 0; off >>= 1) m = fmaxf(m, __shfl_down(m, off));
    __shared__ float pm_[4], psum[4];
    int w = t >> 6, lane = t & 63;
    if (lane == 0) pm_[w] = m;
    __syncthreads();
    float M4 = fmaxf(fmaxf(pm_[0], pm_[1]), fmaxf(pm_[2], pm_[3]));
    float e0 = (t < NP) ? __expf(v0 - M4) : 0.f;
    float e1 = (t + 256 < NP) ? __expf(v1 - M4) : 0.f;
    float s = e0 + e1;
    #pragma unroll
    for (int off = 32; off > 0; off >>= 1) s += __shfl_down(s, off);
    if (lane == 0) psum[w] = s;
    __syncthreads();
    float inv = 1.f / (psum[0] + psum[1] + psum[2] + psum[3]);
    if (t < NP)       S[base + t] = e0 * inv;
    if (t + 256 < NP) S[base + t + 256] = e1 * inv;
}

// ---------------------------------------------------------------------------
// Per-row: sum split-K partials + bias (+resid/relu/cls) -> h0 row; then
// LayerNorm -> xln row, or (final mode, row 0) LN + fc2 -> out[2].
// ---------------------------------------------------------------------------
__global__ __launch_bounds__(256) void rowfuse_kernel(
    const float* __restrict__ P, long slice, int skN, int rowOff,
    const float* __restrict__ bias, int doRelu,
    const float* __restrict__ resid, const float* __restrict__ cls,
    float* __restrict__ h0,
    const float* __restrict__ g, const float* __restrict__ b,
    float* __restrict__ xln,
    const float* __restrict__ fc2w, const float* __restrict__ fc2b,
    float* __restrict__ out)
{
    const int r = blockIdx.x, t = threadIdx.x;
    float v0, v1;
    if (cls && r == 0) {
        v0 = cls[t]; v1 = cls[t + 256];
    } else {
        const float* p = P + (long)(r - rowOff) * DIM;
        v0 = bias[t]; v1 = bias[t + 256];
        for (int k = 0; k < skN; ++k) {
            v0 += p[(long)k * slice + t];
            v1 += p[(long)k * slice + t + 256];
        }
        if (resid) {
            v0 += resid[(long)r * DIM + t];
            v1 += resid[(long)r * DIM + t + 256];
        }
        if (doRelu) { v0 = fmaxf(v0, 0.f); v1 = fmaxf(v1, 0.f); }
    }
    h0[(long)r * DIM + t] = v0;
    h0[(long)r * DIM + t + 256] = v1;
    if (out && r != 0) return;

    float s = v0 + v1, sq = v0 * v0 + v1 * v1;
    #pragma unroll
    for (int off = 32; off > 0; off >>= 1) {
        s += __shfl_down(s, off);
        sq += __shfl_down(sq, off);
    }
    __shared__ float ps[4], pq[4], pc0[4], pc1[4];
    int w = t >> 6, lane = t & 63;
    if (lane == 0) { ps[w] = s; pq[w] = sq; }
    __syncthreads();
    float Sm = ps[0] + ps[1] + ps[2] + ps[3];
    float Q = pq[0] + pq[1] + pq[2] + pq[3];
    float mean = Sm * (1.f / DIM);
    float var = Q * (1.f / DIM) - mean * mean;
    float inv = rsqrtf(var + LN_EPS);
    float n0 = (v0 - mean) * inv * g[t] + b[t];
    float n1 = (v1 - mean) * inv * g[t + 256] + b[t + 256];
    if (!out) {
        xln[(long)r * DIM + t] = n0;
        xln[(long)r * DIM + t + 256] = n1;
    } else {
        float c0 = n0 * fc2w[t * 2]     + n1 * fc2w[(t + 256) * 2];
        float c1 = n0 * fc2w[t * 2 + 1] + n1 * fc2w[(t + 256) * 2 + 1];
        #pragma unroll
        for (int off = 32; off > 0; off >>= 1) {
            c0 += __shfl_down(c0, off);
            c1 += __shfl_down(c1, off);
        }
        if (lane == 0) { pc0[w] = c0; pc1[w] = c1; }
        __syncthreads();
        if (t == 0) {
            out[0] = pc0[0] + pc0[1] + pc0[2] + pc0[3] + fc2b[0];
            out[1] = pc1[0] + pc1[1] + pc1[2] + pc1[3] + fc2b[1];
        }
    }
}

// ---------------------------------------------------------------------------
// Mega init: [0,448) fc1 split-K8 GEMM -> Pp; [448,962) CPB angle tables
// for both layers (per-head planes); [962,1591) pair -> (angle idx, frac).
// ---------------------------------------------------------------------------
__global__ __launch_bounds__(256) void mega_kernel(
    const float* __restrict__ hin, const float* __restrict__ fc1_w,
    const float* __restrict__ w1_0, const float* __restrict__ b1_0,
    const float* __restrict__ w2_0, const float* __restrict__ b2_0,
    const float* __restrict__ w1_1, const float* __restrict__ b1_1,
    const float* __restrict__ w2_1, const float* __restrict__ b2_1,
    const float* __restrict__ coords,
    float* __restrict__ Pp, float* __restrict__ T,
    int* __restrict__ pm, float* __restrict__ pf)
{
    __shared__ float as[16][68], bs[16][68];
    __shared__ float red[4][64][8];
    const int bid = blockIdx.x, tid = threadIdx.x;

    if (bid < 448) {
        // ---- fc1: (400,1024)@(1024,512), skN=8, KS=128 ----
        int sk = bid / 56, rem = bid % 56;
        int m0 = (rem % 7) * 64, n0 = (rem / 7) * 64;
        int kBeg = sk * 128, kEnd = kBeg + 128;
        float acc[4][4] = {};
        auto loadA = [&](int k0, float r[4]) {
            r[0]=r[1]=r[2]=r[3]=0.f;
            int gm = m0 + (tid >> 2);
            if (gm >= 400) return;
            int gk = k0 + (tid & 3) * 4;
            float4 v = *(const float4*)(hin + (long)gm * 1024 + gk);
            r[0]=v.x; r[1]=v.y; r[2]=v.z; r[3]=v.w;
        };
        auto loadB = [&](int k0, float r[4]) {
            int gk = k0 + (tid >> 4);
            int gn = n0 + (tid & 15) * 4;
            float4 v = *(const float4*)(fc1_w + (long)gk * 512 + gn);
            r[0]=v.x; r[1]=v.y; r[2]=v.z; r[3]=v.w;
        };
        gemm64<false>(kBeg, kEnd, tid, as, bs, acc, loadA, loadB);
        float* C = Pp + (long)sk * (400L * 512);
        const int tx = tid & 15, ty = tid >> 4;
        #pragma unroll
        for (int r = 0; r < 4; ++r) {
            int m = m0 + ty * 4 + r;
            if (m >= 400) continue;
            *(float4*)&C[(long)m * 512 + n0 + tx * 4] =
                make_float4(acc[r][0], acc[r][1], acc[r][2], acc[r][3]);
        }
    } else if (bid < 962) {
        // ---- CPB angle tables ----
        int tb = bid - 448;
        int z = tb / 257, ab = tb % 257;
        const float* w1 = z ? w1_1 : w1_0;
        const float* b1 = z ? b1_1 : b1_0;
        const float* w2 = z ? w2_1 : w2_0;
        const float* b2 = z ? b2_1 : b2_0;
        const int lane = tid & 63, wv = tid >> 6;
        float ca = 0.f, sa = 0.f;
        if (ab != 256) {
            float th = fmaf((float)(ab * 64 + lane),
                            (float)(2.0 * M_PI / CPB_M), -(float)M_PI);
            sincosf(th, &sa, &ca);
        } else if (lane == 0) {
            // wrap entry at a = CPB_M (theta = +pi); lanes>0 = zero-vector
            sincosf((float)M_PI, &sa, &ca);
        }
        float a8[8] = {};
        const int kbeg = wv * 128;
        #pragma unroll 4
        for (int k = kbeg; k < kbeg + 128; ++k) {
            float hk = fmaxf(fmaf(ca, w1[k], fmaf(sa, w1[512 + k], b1[k])), 0.f);
            #pragma unroll
            for (int h2 = 0; h2 < 8; ++h2)
                a8[h2] = fmaf(hk, w2[k * 8 + h2], a8[h2]);
        }
        #pragma unroll
        for (int h2 = 0; h2 < 8; ++h2) red[wv][lane][h2] = a8[h2];
        __syncthreads();
        if (tid < 64) {
            int a = ab * 64 + tid;
            #pragma unroll
            for (int h2 = 0; h2 < 8; ++h2)
                T[(long)(z * 8 + h2) * TSTRIDE + a] =
                    red[0][tid][h2] + red[1][tid][h2] +
                    red[2][tid][h2] + red[3][tid][h2] + b2[h2];
        }
    } else {
        // ---- pair -> (angle index, frac), layer-independent ----
        int p = (bid - 962) * 256 + tid;
        if (p < NP * NP) {
            int i = p / NP, j = p - i * NP;
            float xi = (i == 0) ? 0.f : coords[(i - 1) * 2];
            float yi = (i == 0) ? 0.f : coords[(i - 1) * 2 + 1];
            float xj = (j == 0) ? 0.f : coords[(j - 1) * 2];
            float yj = (j == 0) ? 0.f : coords[(j - 1) * 2 + 1];
            float rx = xi - xj, ry = yi - yj;
            int mm; float fr;
            if (rx == 0.f && ry == 0.f) {
                mm = CPB_M + 1; fr = 0.f;    // zero-vector entries
            } else {
                float x = (atan2f(ry, rx) + 3.14159265358979f)
                          * (float)(CPB_M / (2.0 * M_PI));
                int mi = (int)x;
                fr = x - (float)mi;
                mm = (mi >= CPB_M) ? mi - CPB_M : mi;
            }
            pm[i * 416 + j] = mm;
            pf[i * 416 + j] = fr;
        }
    }
}

// ---------------------------------------------------------------------------
extern "C" void kernel_launch(void* const* d_in, const int* in_sizes, int n_in,
                              void* d_out, int out_size, void* d_ws, size_t ws_size,
                              hipStream_t stream)
{
    const float* h      = (const float*)d_in[0];
    const float* coords = (const float*)d_in[1];
    const float* fc1_w  = (const float*)d_in[2];
    const float* fc1_b  = (const float*)d_in[3];
    const float* cls    = (const float*)d_in[4];
    const float* norm_g = (const float*)d_in[25];
    const float* norm_b = (const float*)d_in[26];
    const float* fc2_w  = (const float*)d_in[27];
    const float* fc2_b  = (const float*)d_in[28];

    float* ws  = (float*)d_ws;
    float* h0  = ws;                       // 401*512
    float* xln = h0  + 401L * 512;         // 401*512
    float* att = xln + 401L * 512;         // 401*512
    float* S   = att + 401L * 512;         // 8*PLANE
    float* T   = S   + 8L * PLANE;         // 2*8*TSTRIDE
    int*   pm  = (int*)(T + 16L * TSTRIDE);         // 401*416
    float* pf  = (float*)(pm + 401L * 416);         // 401*416
    float* Pq  = pf + 401L * 416;          // 2*401*1536
    float* Pv  = Pq + 2L * 401 * 1536;     // 8*401*512
    float* Pp  = Pv + 8L * 401 * 512;      // 8*401*512

    mega_kernel<<<1591, 256, 0, stream>>>(
        h, fc1_w,
        (const float*)d_in[7],  (const float*)d_in[8],
        (const float*)d_in[9],  (const float*)d_in[10],
        (const float*)d_in[17], (const float*)d_in[18],
        (const float*)d_in[19], (const float*)d_in[20],
        coords, Pp, T, pm, pf);

    // fc1 partial reduce + relu + cls row + LN (layer-1 norm) -> h0, xln
    rowfuse_kernel<<<401, 256, 0, stream>>>(
        Pp, 400L * 512, 8, 1, fc1_b, 1, nullptr, cls, h0,
        (const float*)d_in[5], (const float*)d_in[6], xln,
        nullptr, nullptr, nullptr);

    for (int l = 0; l < 2; ++l) {
        int base = 5 + 10 * l;
        const float* qkv_w  = (const float*)d_in[base + 6];
        const float* qkv_b  = (const float*)d_in[base + 7];
        const float* proj_w = (const float*)d_in[base + 8];
        const float* proj_b = (const float*)d_in[base + 9];

        // qkv: (401,512)@(512,1536), split-K2 -> Pq (raw; bias folded later)
        gemm_split_kernel<<<dim3(7, 24, 2), 256, 0, stream>>>(
            xln, 512, qkv_w, 1536, Pq, 1536, 401L * 1536, 401, 1536, 512, 2);

        qk_kernel<<<dim3(7, 7, 8), 256, 0, stream>>>(
            Pq, qkv_b, pm, pf, T + (long)l * 8 * TSTRIDE, S);

        softmax_kernel<<<dim3(401, 8), 256, 0, stream>>>(S);

        pv_kernel<<<dim3(7, 1, 64), 256, 0, stream>>>(S, Pq, qkv_b, Pv);
        att_reduce_kernel<<<201, 256, 0, stream>>>(Pv, att);

        // proj: (401,512)@(512,512), split-K8 -> Pp
        gemm_split_kernel<<<dim3(7, 8, 8), 256, 0, stream>>>(
            att, 512, proj_w, 512, Pp, 512, 401L * 512, 401, 512, 512, 8);

        if (l == 0) {
            // h0 += proj; LN with layer-2 norm -> xln
            rowfuse_kernel<<<401, 256, 0, stream>>>(
                Pp, 401L * 512, 8, 0, proj_b, 0, h0, nullptr, h0,
                (const float*)d_in[15], (const float*)d_in[16], xln,
                nullptr, nullptr, nullptr);
        } else {
            // h0 += proj; final LN (row 0) + fc2 -> out
            rowfuse_kernel<<<401, 256, 0, stream>>>(
                Pp, 401L * 512, 8, 0, proj_b, 0, h0, nullptr, h0,
                norm_g, norm_b, nullptr, fc2_w, fc2_b, (float*)d_out);
        }
    }
}